// Round 3
// baseline (47135.318 us; speedup 1.0000x reference)
//
#include <hip/hip_runtime.h>

#define NV 262144          // 64^3

// ---------------- Gaussian weights (13-tap, sigma=2) ----------------
static __device__ __forceinline__ void gauss_weights(float K[13]) {
  float s = 0.f;
#pragma unroll
  for (int j = 0; j < 13; ++j) {
    float r = (float)(j - 6);
    K[j] = expf(-0.125f * r * r);
    s += K[j];
  }
#pragma unroll
  for (int j = 0; j < 13; ++j) K[j] = K[j] / s;
}

// ---------------- trilinear helpers (align_corners=True, border padding) ----------------
static __device__ __forceinline__ void tl_make(float gx, float gy, float gz,
                                               int sx, int sy, int sz,
                                               int id[8], float wt[8]) {
  float x = fminf(fmaxf((gx + 1.0f) * 0.5f * 63.0f, 0.0f), 63.0f);
  float y = fminf(fmaxf((gy + 1.0f) * 0.5f * 63.0f, 0.0f), 63.0f);
  float z = fminf(fmaxf((gz + 1.0f) * 0.5f * 63.0f, 0.0f), 63.0f);
  float x0f = floorf(x), y0f = floorf(y), z0f = floorf(z);
  int x0 = (int)x0f, y0 = (int)y0f, z0 = (int)z0f;
  int x1 = min(x0 + 1, 63), y1 = min(y0 + 1, 63), z1 = min(z0 + 1, 63);
  float wx = x - x0f, wy = y - y0f, wz = z - z0f;
  float ux = 1.f - wx, uy = 1.f - wy, uz = 1.f - wz;
  int X0 = x0 * sx, X1 = x1 * sx, Y0 = y0 * sy, Y1 = y1 * sy, Z0 = z0 * sz, Z1 = z1 * sz;
  id[0] = Z0 + Y0 + X0; wt[0] = uz * uy * ux;
  id[1] = Z0 + Y0 + X1; wt[1] = uz * uy * wx;
  id[2] = Z0 + Y1 + X0; wt[2] = uz * wy * ux;
  id[3] = Z0 + Y1 + X1; wt[3] = uz * wy * wx;
  id[4] = Z1 + Y0 + X0; wt[4] = wz * uy * ux;
  id[5] = Z1 + Y0 + X1; wt[5] = wz * uy * wx;
  id[6] = Z1 + Y1 + X0; wt[6] = wz * wy * ux;
  id[7] = Z1 + Y1 + X1; wt[7] = wz * wy * wx;
}

static __device__ __forceinline__ float tl_apply(const float* __restrict__ img,
                                                 const int id[8], const float wt[8]) {
  float s = 0.f;
#pragma unroll
  for (int k = 0; k < 8; ++k) s = fmaf(wt[k], img[id[k]], s);
  return s;
}

// ---------------- init ----------------
__global__ void init_kernel(const float* __restrict__ src, const float* __restrict__ tgt,
                            const float* __restrict__ z0,
                            float* __restrict__ cin, float* __restrict__ rd0,
                            float* __restrict__ phi0, float* __restrict__ outRes0) {
  int idx = blockIdx.x * 256 + threadIdx.x;
  int d = idx >> 12, h = (idx >> 6) & 63, w = idx & 63;
  float z = z0[idx];
  cin[idx] = z;                  // residual
  cin[NV + idx] = src[idx];      // image
  cin[2 * NV + idx] = tgt[idx];  // target (constant)
  cin[3 * NV + idx] = 0.f;       // zero pad channel
  outRes0[idx] = z;
  rd0[idx] = 0.f;
  const float step = 2.0f / 63.0f;
  phi0[idx] = -1.f + w * step;
  phi0[NV + idx] = -1.f + h * step;
  phi0[2 * NV + idx] = -1.f + d * step;
}

// ---------------- spatial gradient ----------------
__global__ void grad_kernel(const float* __restrict__ img, float* __restrict__ gout) {
  int idx = blockIdx.x * 256 + threadIdx.x;
  int d = idx >> 12, h = (idx >> 6) & 63, w = idx & 63;
  int wp = min(w + 1, 63), wm = max(w - 1, 0);
  int hp = min(h + 1, 63), hm = max(h - 1, 0);
  int dp = min(d + 1, 63), dm = max(d - 1, 0);
  int bd = d << 12, bh = h << 6;
  gout[idx]          = 0.5f * (img[bd + bh + wp] - img[bd + bh + wm]);
  gout[NV + idx]     = 0.5f * (img[bd + (hp << 6) + w] - img[bd + (hm << 6) + w]);
  gout[2 * NV + idx] = 0.5f * (img[(dp << 12) + bh + w] - img[(dm << 12) + bh + w]);
}

// ---------------- Gaussian smoothing ----------------
__global__ void smooth_d_fused(const float* __restrict__ residual, const float* __restrict__ g,
                               float* __restrict__ out) {
  int idx = blockIdx.x * 256 + threadIdx.x;
  int c = blockIdx.y;
  int d = idx >> 12;
  float K[13]; gauss_weights(K);
  const float* gc = g + (size_t)c * NV;
  float acc = 0.f;
#pragma unroll
  for (int j = 0; j < 13; ++j) {
    int dd = d + j - 6;
    if ((unsigned)dd < 64u) {
      int o = idx + ((j - 6) << 12);
      acc = fmaf(K[j], -residual[o] * gc[o], acc);
    }
  }
  out[(size_t)c * NV + idx] = acc;
}

template <int SHIFT>
__global__ void smooth_axis(const float* __restrict__ in, float* __restrict__ out) {
  int idx = blockIdx.x * 256 + threadIdx.x;
  int c = blockIdx.y;
  int pos = (idx >> SHIFT) & 63;
  float K[13]; gauss_weights(K);
  const float* ic = in + (size_t)c * NV;
  float acc = 0.f;
#pragma unroll
  for (int j = 0; j < 13; ++j) {
    int pp = pos + j - 6;
    if ((unsigned)pp < 64u) acc = fmaf(K[j], ic[idx + ((j - 6) << SHIFT)], acc);
  }
  out[(size_t)c * NV + idx] = acc;
}

// ---------------- fields output ----------------
__global__ void field_def_kernel(const float* __restrict__ v, float* __restrict__ fout) {
  int idx = blockIdx.x * 256 + threadIdx.x;
  int p = idx >> 12, q = (idx >> 6) & 63, r = idx & 63;
  int tidx = (r << 12) + (q << 6) + p;
  fout[idx * 3 + 0] = v[tidx];
  fout[idx * 3 + 1] = v[NV + tidx];
  fout[idx * 3 + 2] = v[2 * NV + tidx];
}

// ---------------- register-blocked conv: NGRP*4 in-channels -> 50 out, LeakyReLU ----------------
// tile 4x4x4 voxels, halo 6^3=216/channel; 256 threads = 4 waves; wave w owns outputs
// [w*13, w*13+13) (o>=50 has zero-padded weights). Channels staged 4 at a time,
// LDS double-buffered with register prefetch. wt layout: [ci][tap27][o pad 52].
template <int NGRP>
__global__ __launch_bounds__(256) void conv_fwd(const float* __restrict__ in,
                                                const float* __restrict__ wt,
                                                float* __restrict__ outp) {
  __shared__ float sh[2][4 * 216];
  const int tid = threadIdx.x;
  const int lane = tid & 63;
  const int tx = lane & 3, ty = (lane >> 2) & 3, tz = lane >> 4;
  const int wb = __builtin_amdgcn_readfirstlane((tid >> 6) * 13);
  int bw = blockIdx.x * 4, bh = blockIdx.y * 4, bd = blockIdx.z * 4;

  int offs[4]; bool vok[4];
#pragma unroll
  for (int k = 0; k < 4; ++k) {
    int s = tid + k * 256;
    int ch = s / 216; int r = s - ch * 216;
    int lz = r / 36; int r2 = r - lz * 36; int ly = r2 / 6; int lx = r2 - ly * 6;
    int gz = bd + lz - 1, gy = bh + ly - 1, gx = bw + lx - 1;
    bool ok = (s < 864) && ((unsigned)gz < 64u) && ((unsigned)gy < 64u) && ((unsigned)gx < 64u);
    vok[k] = ok;
    offs[k] = ok ? (ch * NV + (gz << 12) + (gy << 6) + gx) : 0;
  }

  float acc[13];
#pragma unroll
  for (int o = 0; o < 13; ++o) acc[o] = 0.f;

  float rv[4];
#pragma unroll
  for (int k = 0; k < 4; ++k) rv[k] = vok[k] ? in[offs[k]] : 0.f;
#pragma unroll
  for (int k = 0; k < 4; ++k) { int s = tid + k * 256; if (s < 864) sh[0][s] = rv[k]; }
  __syncthreads();

  for (int g = 0; g < NGRP; ++g) {
    if (g + 1 < NGRP) {
      const float* nin = in + (size_t)(g + 1) * 4 * NV;
#pragma unroll
      for (int k = 0; k < 4; ++k) rv[k] = vok[k] ? nin[offs[k]] : 0.f;
    }
    const float* shc = sh[g & 1];
    const float* wg = wt + (size_t)g * 4 * 27 * 52 + wb;
#pragma unroll
    for (int cc = 0; cc < 4; ++cc) {
#pragma unroll
      for (int tap = 0; tap < 27; ++tap) {
        const int kd = tap / 9, kh = (tap / 3) % 3, kw = tap % 3;
        float xv = shc[cc * 216 + (tz + kd) * 36 + (ty + kh) * 6 + (tx + kw)];
        const float* wrow = wg + (cc * 27 + tap) * 52;
#pragma unroll
        for (int o = 0; o < 13; ++o) acc[o] = fmaf(xv, wrow[o], acc[o]);
      }
    }
    __syncthreads();
    if (g + 1 < NGRP) {
#pragma unroll
      for (int k = 0; k < 4; ++k) { int s = tid + k * 256; if (s < 864) sh[(g + 1) & 1][s] = rv[k]; }
    }
    __syncthreads();
  }

  int idx = ((bd + tz) << 12) + ((bh + ty) << 6) + (bw + tx);
#pragma unroll
  for (int o = 0; o < 13; ++o) {
    if (wb + o < 50) {
      float v = acc[o];
      outp[(size_t)(wb + o) * NV + idx] = (v >= 0.f) ? v : 0.01f * v;
    }
  }
}

// ---------------- conv3 (50 -> 1) + residual update, double-buffered ----------------
__global__ __launch_bounds__(256) void conv3_fwd(const float* __restrict__ x2,
                                                 const float* __restrict__ w3,
                                                 float* __restrict__ residual,
                                                 float* __restrict__ resOut) {
  __shared__ float sh[2][1200];
  const int tid = threadIdx.x;
  int tx = tid & 7, ty = (tid >> 3) & 7, tz = tid >> 6;
  int w0 = blockIdx.x * 8, h0 = blockIdx.y * 8, d0 = blockIdx.z * 4;

  int offs[5]; bool vok[5];
#pragma unroll
  for (int k = 0; k < 5; ++k) {
    int s = tid + k * 256;
    int ch = (s >= 600) ? 1 : 0;
    int r = s - ch * 600;
    int lz = r / 100; int r2 = r - lz * 100; int ly = r2 / 10; int lx = r2 - ly * 10;
    int gz = d0 + lz - 1, gy = h0 + ly - 1, gx = w0 + lx - 1;
    bool ok = (s < 1200) && ((unsigned)gz < 64u) && ((unsigned)gy < 64u) && ((unsigned)gx < 64u);
    vok[k] = ok;
    offs[k] = ok ? (ch * NV + (gz << 12) + (gy << 6) + gx) : 0;
  }

  float acc = 0.f;
  float rv[5];
#pragma unroll
  for (int k = 0; k < 5; ++k) rv[k] = vok[k] ? x2[offs[k]] : 0.f;
#pragma unroll
  for (int k = 0; k < 5; ++k) { int s = tid + k * 256; if (s < 1200) sh[0][s] = rv[k]; }
  __syncthreads();

  int cur = 0;
  for (int ci = 0; ci < 50; ci += 2) {
    if (ci + 2 < 50) {
      const float* nin = x2 + (size_t)(ci + 2) * NV;
#pragma unroll
      for (int k = 0; k < 5; ++k) rv[k] = vok[k] ? nin[offs[k]] : 0.f;
    }
    const float* shc = sh[cur];
#pragma unroll
    for (int cc = 0; cc < 2; ++cc) {
      const float* wr = w3 + (ci + cc) * 27;
#pragma unroll
      for (int kd = 0; kd < 3; ++kd)
#pragma unroll
        for (int kh = 0; kh < 3; ++kh)
#pragma unroll
          for (int kw = 0; kw < 3; ++kw) {
            float xv = shc[cc * 600 + (tz + kd) * 100 + (ty + kh) * 10 + (tx + kw)];
            acc = fmaf(xv, wr[(kd * 3 + kh) * 3 + kw], acc);
          }
    }
    __syncthreads();
    if (ci + 2 < 50) {
#pragma unroll
      for (int k = 0; k < 5; ++k) { int s = tid + k * 256; if (s < 1200) sh[cur ^ 1][s] = rv[k]; }
    }
    __syncthreads();
    cur ^= 1;
  }

  int idx = ((d0 + tz) << 12) + ((h0 + ty) << 6) + (w0 + tx);
  float nr = residual[idx] + acc / 10.0f;
  residual[idx] = nr;
  resOut[idx] = nr;
}

// ---------------- res_def warp + add residual (def recomputed from v) ----------------
__global__ void resdef_kernel(const float* __restrict__ rdOld, const float* __restrict__ v,
                              const float* __restrict__ residual, float* __restrict__ rdNew,
                              int doSample) {
  int idx = blockIdx.x * 256 + threadIdx.x;
  float val = 0.f;
  if (doSample) {
    int p = idx >> 12, q = (idx >> 6) & 63, r = idx & 63;
    int tidx = (r << 12) + (q << 6) + p;
    const float step = 2.0f / 63.0f;
    float gx = (-1.f + r * step) - v[tidx] / 10.0f;
    float gy = (-1.f + q * step) - v[NV + tidx] / 10.0f;
    float gz = (-1.f + p * step) - v[2 * NV + tidx] / 10.0f;
    int id[8]; float wt[8];
    tl_make(gx, gy, gz, 1, 64, 4096, id, wt);
    val = tl_apply(rdOld, id, wt);
  }
  rdNew[idx] = val + residual[idx];
}

// ---------------- fused phi warp + image update ----------------
__global__ void phi_image_kernel(const float* __restrict__ v, const float* __restrict__ phiOld,
                                 float* __restrict__ phiNew, const float* __restrict__ src,
                                 const float* __restrict__ seg, const float* __restrict__ rd,
                                 float* __restrict__ image) {
  int idx = blockIdx.x * 256 + threadIdx.x;
  int d = idx >> 12, h = (idx >> 6) & 63, w = idx & 63;
  const float step = 2.0f / 63.0f;
  float gx = (-1.f + d * step) - v[idx] / 10.0f;
  float gy = (-1.f + h * step) - v[NV + idx] / 10.0f;
  float gz = (-1.f + w * step) - v[2 * NV + idx] / 10.0f;
  int id[8]; float wt[8];
  tl_make(gx, gy, gz, 4096, 64, 1, id, wt);
  float px = tl_apply(phiOld, id, wt);
  float py = tl_apply(phiOld + NV, id, wt);
  float pz = tl_apply(phiOld + 2 * NV, id, wt);
  phiNew[idx] = px;
  phiNew[NV + idx] = py;
  phiNew[2 * NV + idx] = pz;
  int id2[8]; float wt2[8];
  tl_make(px, py, pz, 1, 64, 4096, id2, wt2);
  float sval = tl_apply(src, id2, wt2);
  float mval = tl_apply(seg, id2, wt2);
  image[idx] = sval + rd[idx] * 4.0e-05f * mval;   // MU^2/L
}

// ---------------- weight transposes (dest-indexed) ----------------
// wt1: [i][ci=4][tap=27][o pad 52]; ci==3 and o>=50 are zero
__global__ void wt1_kernel(const float* __restrict__ W1, float* __restrict__ wt1) {
  int gid = blockIdx.x * 256 + threadIdx.x;
  if (gid >= 10 * 4 * 27 * 52) return;
  int o = gid % 52; int rest = gid / 52;
  int t = rest % 27; rest /= 27;
  int ci = rest % 4; int i = rest / 4;
  float v = 0.f;
  if (ci < 3 && o < 50) v = W1[(((size_t)i * 50 + o) * 3 + ci) * 27 + t];
  wt1[gid] = v;
}

// wt2: [i][ci pad 52][tap=27][o pad 52]; ci>=50 or o>=50 are zero
__global__ void wt2_kernel(const float* __restrict__ W2, float* __restrict__ wt2) {
  int gid = blockIdx.x * 256 + threadIdx.x;
  if (gid >= 10 * 52 * 27 * 52) return;
  int o = gid % 52; int rest = gid / 52;
  int t = rest % 27; rest /= 27;
  int ci = rest % 52; int i = rest / 52;
  float v = 0.f;
  if (o < 50 && ci < 50) v = W2[(((size_t)i * 50 + o) * 50 + ci) * 27 + t];
  wt2[gid] = v;
}

// ---------------- final copy ----------------
__global__ void final_copy(const float* __restrict__ image, const float* __restrict__ rd,
                           float* __restrict__ outImg, float* __restrict__ outRd) {
  int idx = blockIdx.x * 256 + threadIdx.x;
  outImg[idx] = image[idx];
  outRd[idx] = rd[idx];
}

extern "C" void kernel_launch(void* const* d_in, const int* in_sizes, int n_in,
                              void* d_out, int out_size, void* d_ws, size_t ws_size,
                              hipStream_t stream) {
  const float* src = (const float*)d_in[0];
  const float* tgt = (const float*)d_in[1];
  const float* seg = (const float*)d_in[2];
  const float* z0  = (const float*)d_in[3];
  const float* W1  = (const float*)d_in[4];
  const float* W2  = (const float*)d_in[5];
  const float* W3  = (const float*)d_in[6];
  float* out = (float*)d_out;
  float* ws = (float*)d_ws;

  const size_t N = NV;
  float* cin      = ws;                    // 4 planes
  float* residual = cin;
  float* image    = cin + N;
  float* rdb[2]   = { ws + 4 * N, ws + 5 * N };
  float* phib[2]  = { ws + 6 * N, ws + 9 * N };    // 3 planes each
  float* vbuf     = ws + 12 * N;                   // 3 planes
  float* x1       = ws + 15 * N;                   // 52 planes (pad)
  float* x2       = ws + 67 * N;                   // 50 planes
  float* t1       = x1;                            // reuse (dead before conv1)
  float* t2       = x1 + 3 * N;
  float* wt1      = ws + 117 * N;                  // 56160
  float* wt2      = wt1 + 10 * 4 * 27 * 52;        // 730080

  size_t needed = (117 * N + 10 * 4 * 27 * 52 + (size_t)10 * 52 * 27 * 52) * sizeof(float);
  if (ws_size < needed) return;

  float* out_image  = out;
  float* out_fields = out + N;
  float* out_grads  = out + 31 * N;
  float* out_resid  = out + 61 * N;
  float* out_rd     = out + 72 * N;

  dim3 blk(256);
  dim3 grdN((unsigned)(N / 256));
  dim3 grd3((unsigned)(N / 256), 3);
  dim3 cgrd(16, 16, 16);
  dim3 c3grd(8, 8, 16);

  init_kernel<<<grdN, blk, 0, stream>>>(src, tgt, z0, cin, rdb[0], phib[0], out_resid);
  wt1_kernel<<<(10 * 4 * 27 * 52 + 255) / 256, blk, 0, stream>>>(W1, wt1);
  wt2_kernel<<<(10 * 52 * 27 * 52 + 255) / 256, blk, 0, stream>>>(W2, wt2);

  int rc = 0, pc = 0;
  for (int i = 0; i < 10; ++i) {
    grad_kernel<<<grdN, blk, 0, stream>>>(image, out_grads + (size_t)i * 3 * N);

    smooth_d_fused<<<grd3, blk, 0, stream>>>(residual, out_grads + (size_t)i * 3 * N, t1);
    smooth_axis<6><<<grd3, blk, 0, stream>>>(t1, t2);
    smooth_axis<0><<<grd3, blk, 0, stream>>>(t2, vbuf);

    field_def_kernel<<<grdN, blk, 0, stream>>>(vbuf, out_fields + (size_t)i * 3 * N);

    conv_fwd<1><<<cgrd, blk, 0, stream>>>(cin, wt1 + (size_t)i * 4 * 27 * 52, x1);
    conv_fwd<13><<<cgrd, blk, 0, stream>>>(x1, wt2 + (size_t)i * 52 * 27 * 52, x2);
    conv3_fwd<<<c3grd, blk, 0, stream>>>(x2, W3 + (size_t)i * 1350, residual,
                                         out_resid + (size_t)(i + 1) * N);

    resdef_kernel<<<grdN, blk, 0, stream>>>(rdb[rc], vbuf, residual, rdb[1 - rc],
                                            i > 0 ? 1 : 0);
    rc = 1 - rc;

    phi_image_kernel<<<grdN, blk, 0, stream>>>(vbuf, phib[pc], phib[1 - pc], src, seg,
                                               rdb[rc], image);
    pc = 1 - pc;
  }

  final_copy<<<grdN, blk, 0, stream>>>(image, rdb[rc], out_image, out_rd);
}

// Round 4
// 2987.584 us; speedup vs baseline: 15.7771x; 15.7771x over previous
//
#include <hip/hip_runtime.h>

#define NV 262144          // 64^3

using bf16x8 = __attribute__((ext_vector_type(8))) short;
using f32x4  = __attribute__((ext_vector_type(4))) float;

static __device__ __forceinline__ unsigned short f2bf(float x) {
  unsigned int u = __float_as_uint(x);
  unsigned int r = (u + 0x7FFFu + ((u >> 16) & 1u)) >> 16;
  return (unsigned short)r;
}

// ---------------- Gaussian weights (13-tap, sigma=2) ----------------
static __device__ __forceinline__ void gauss_weights(float K[13]) {
  float s = 0.f;
#pragma unroll
  for (int j = 0; j < 13; ++j) {
    float r = (float)(j - 6);
    K[j] = expf(-0.125f * r * r);
    s += K[j];
  }
#pragma unroll
  for (int j = 0; j < 13; ++j) K[j] = K[j] / s;
}

// ---------------- trilinear helpers ----------------
static __device__ __forceinline__ void tl_make(float gx, float gy, float gz,
                                               int sx, int sy, int sz,
                                               int id[8], float wt[8]) {
  float x = fminf(fmaxf((gx + 1.0f) * 0.5f * 63.0f, 0.0f), 63.0f);
  float y = fminf(fmaxf((gy + 1.0f) * 0.5f * 63.0f, 0.0f), 63.0f);
  float z = fminf(fmaxf((gz + 1.0f) * 0.5f * 63.0f, 0.0f), 63.0f);
  float x0f = floorf(x), y0f = floorf(y), z0f = floorf(z);
  int x0 = (int)x0f, y0 = (int)y0f, z0 = (int)z0f;
  int x1 = min(x0 + 1, 63), y1 = min(y0 + 1, 63), z1 = min(z0 + 1, 63);
  float wx = x - x0f, wy = y - y0f, wz = z - z0f;
  float ux = 1.f - wx, uy = 1.f - wy, uz = 1.f - wz;
  int X0 = x0 * sx, X1 = x1 * sx, Y0 = y0 * sy, Y1 = y1 * sy, Z0 = z0 * sz, Z1 = z1 * sz;
  id[0] = Z0 + Y0 + X0; wt[0] = uz * uy * ux;
  id[1] = Z0 + Y0 + X1; wt[1] = uz * uy * wx;
  id[2] = Z0 + Y1 + X0; wt[2] = uz * wy * ux;
  id[3] = Z0 + Y1 + X1; wt[3] = uz * wy * wx;
  id[4] = Z1 + Y0 + X0; wt[4] = wz * uy * ux;
  id[5] = Z1 + Y0 + X1; wt[5] = wz * uy * wx;
  id[6] = Z1 + Y1 + X0; wt[6] = wz * wy * ux;
  id[7] = Z1 + Y1 + X1; wt[7] = wz * wy * wx;
}

static __device__ __forceinline__ float tl_apply(const float* __restrict__ img,
                                                 const int id[8], const float wt[8]) {
  float s = 0.f;
#pragma unroll
  for (int k = 0; k < 8; ++k) s = fmaf(wt[k], img[id[k]], s);
  return s;
}

// ---------------- init ----------------
__global__ void init_kernel(const float* __restrict__ src, const float* __restrict__ z0,
                            float* __restrict__ residual, float* __restrict__ image,
                            float* __restrict__ rd0, float* __restrict__ phi0,
                            float* __restrict__ outRes0) {
  int idx = blockIdx.x * 256 + threadIdx.x;
  int d = idx >> 12, h = (idx >> 6) & 63, w = idx & 63;
  float z = z0[idx];
  residual[idx] = z;
  outRes0[idx] = z;
  image[idx] = src[idx];
  rd0[idx] = 0.f;
  const float step = 2.0f / 63.0f;
  phi0[idx] = -1.f + w * step;
  phi0[NV + idx] = -1.f + h * step;
  phi0[2 * NV + idx] = -1.f + d * step;
}

// ---------------- spatial gradient ----------------
__global__ void grad_kernel(const float* __restrict__ img, float* __restrict__ gout) {
  int idx = blockIdx.x * 256 + threadIdx.x;
  int d = idx >> 12, h = (idx >> 6) & 63, w = idx & 63;
  int wp = min(w + 1, 63), wm = max(w - 1, 0);
  int hp = min(h + 1, 63), hm = max(h - 1, 0);
  int dp = min(d + 1, 63), dm = max(d - 1, 0);
  int bd = d << 12, bh = h << 6;
  gout[idx]          = 0.5f * (img[bd + bh + wp] - img[bd + bh + wm]);
  gout[NV + idx]     = 0.5f * (img[bd + (hp << 6) + w] - img[bd + (hm << 6) + w]);
  gout[2 * NV + idx] = 0.5f * (img[(dp << 12) + bh + w] - img[(dm << 12) + bh + w]);
}

// ---------------- Gaussian smoothing ----------------
__global__ void smooth_d_fused(const float* __restrict__ residual, const float* __restrict__ g,
                               float* __restrict__ out) {
  int idx = blockIdx.x * 256 + threadIdx.x;
  int c = blockIdx.y;
  int d = idx >> 12;
  float K[13]; gauss_weights(K);
  const float* gc = g + (size_t)c * NV;
  float acc = 0.f;
#pragma unroll
  for (int j = 0; j < 13; ++j) {
    int dd = d + j - 6;
    if ((unsigned)dd < 64u) {
      int o = idx + ((j - 6) << 12);
      acc = fmaf(K[j], -residual[o] * gc[o], acc);
    }
  }
  out[(size_t)c * NV + idx] = acc;
}

template <int SHIFT>
__global__ void smooth_axis(const float* __restrict__ in, float* __restrict__ out) {
  int idx = blockIdx.x * 256 + threadIdx.x;
  int c = blockIdx.y;
  int pos = (idx >> SHIFT) & 63;
  float K[13]; gauss_weights(K);
  const float* ic = in + (size_t)c * NV;
  float acc = 0.f;
#pragma unroll
  for (int j = 0; j < 13; ++j) {
    int pp = pos + j - 6;
    if ((unsigned)pp < 64u) acc = fmaf(K[j], ic[idx + ((j - 6) << SHIFT)], acc);
  }
  out[(size_t)c * NV + idx] = acc;
}

// ---------------- fields output ----------------
__global__ void field_def_kernel(const float* __restrict__ v, float* __restrict__ fout) {
  int idx = blockIdx.x * 256 + threadIdx.x;
  int p = idx >> 12, q = (idx >> 6) & 63, r = idx & 63;
  int tidx = (r << 12) + (q << 6) + p;
  fout[idx * 3 + 0] = v[tidx];
  fout[idx * 3 + 1] = v[NV + tidx];
  fout[idx * 3 + 2] = v[2 * NV + tidx];
}

// ---------------- conv staging macro (R1-proven) ----------------
#define STAGE_TILE(SRCPTR)                                                        \
  __syncthreads();                                                                \
  for (int s = threadIdx.x; s < 600; s += 256) {                                  \
    int lz = s / 100; int r2 = s - lz * 100; int ly = r2 / 10; int lx = r2 - ly * 10; \
    int gz = d0 + lz - 1, gy = h0 + ly - 1, gx = w0 + lx - 1;                     \
    float val = 0.f;                                                              \
    if ((unsigned)gz < 64u && (unsigned)gy < 64u && (unsigned)gx < 64u)           \
      val = (SRCPTR)[(gz << 12) + (gy << 6) + gx];                                \
    sh[s] = val;                                                                  \
  }                                                                               \
  __syncthreads();

// ---------------- conv1: 3 -> 50, R1 structure, bf16 channel-last output ----------------
__global__ __launch_bounds__(256) void conv1_kernel(const float* __restrict__ zin,
                                                    const float* __restrict__ img,
                                                    const float* __restrict__ tgt,
                                                    const float* __restrict__ wt,
                                                    unsigned short* __restrict__ x1b) {
  __shared__ float sh[600];
  int tx = threadIdx.x & 7, ty = (threadIdx.x >> 3) & 7, tz = threadIdx.x >> 6;
  int w0 = blockIdx.x * 8, h0 = blockIdx.y * 8, d0 = blockIdx.z * 4;
  float acc[50];
#pragma unroll
  for (int o = 0; o < 50; ++o) acc[o] = 0.f;
  for (int ci = 0; ci < 3; ++ci) {
    const float* src = (ci == 0) ? zin : (ci == 1 ? img : tgt);
    STAGE_TILE(src)
    const float* wci = wt + ci * 27 * 52;
#pragma unroll
    for (int kd = 0; kd < 3; ++kd)
#pragma unroll
      for (int kh = 0; kh < 3; ++kh)
#pragma unroll
        for (int kw = 0; kw < 3; ++kw) {
          float xv = sh[(tz + kd) * 100 + (ty + kh) * 10 + (tx + kw)];
          const float* wrow = wci + ((kd * 3 + kh) * 3 + kw) * 52;
#pragma unroll
          for (int o = 0; o < 50; ++o) acc[o] = fmaf(xv, wrow[o], acc[o]);
        }
  }
  int idx = ((d0 + tz) << 12) + ((h0 + ty) << 6) + (w0 + tx);
  unsigned int base = (unsigned int)idx * 64u;
#pragma unroll
  for (int o = 0; o < 64; o += 2) {
    float v0 = 0.f, v1 = 0.f;
    if (o < 50)     { float a = acc[o];     v0 = (a >= 0.f) ? a : 0.01f * a; }
    if (o + 1 < 50) { float a = acc[o + 1]; v1 = (a >= 0.f) ? a : 0.01f * a; }
    unsigned int pk = (unsigned int)f2bf(v0) | ((unsigned int)f2bf(v1) << 16);
    *(unsigned int*)(x1b + base + o) = pk;
  }
}

// ---------------- conv2: MFMA implicit GEMM (50->50) ----------------
// x1b: [NV][64] bf16 channel-last. wtm: per-layer fragment-ordered weights
// [g=4][c=14][mf=4][lane=64][j=8] bf16. Output x2: [50][NV] f32 + LeakyReLU.
// Block: 256 thr = 4 waves, tile W16 x H8 x D4 (wave = d-slice). Halo 18x10x6.
// LDS: [hpos][16 ci] bf16, row stride 48B (32B data + 16B pad for bank spread).
__global__ __launch_bounds__(256) void conv2_mfma(const unsigned short* __restrict__ x1b,
                                                  const unsigned short* __restrict__ wtm,
                                                  float* __restrict__ x2) {
  __shared__ char sh[1080 * 48];
  const int tid = threadIdx.x;
  const int lane = tid & 63;
  const int wv = tid >> 6;          // wave id = d_local (0..3)
  const int ww = lane & 15;         // spatial w within fragment
  const int kb = lane >> 4;         // k sub-block (0..3)
  const int w0 = blockIdx.x * 16, h0 = blockIdx.y * 8, d0 = blockIdx.z * 4;

  // ---- precompute staging slots: 2160 x 16B units, 9 per thread ----
  int gofs[9]; int lofs[9]; bool gok[9]; bool sval[9];
#pragma unroll
  for (int k = 0; k < 9; ++k) {
    int s = tid + k * 256;
    sval[k] = (s < 2160);
    int hpos = s >> 1, q = s & 1;
    int wws = hpos % 18; int rest = hpos / 18;
    int hh = rest % 10;  int dd = rest / 10;
    int gz = d0 + dd - 1, gy = h0 + hh - 1, gx = w0 + wws - 1;
    bool ok = sval[k] && ((unsigned)gz < 64u) && ((unsigned)gy < 64u) && ((unsigned)gx < 64u);
    gok[k] = ok;
    gofs[k] = ok ? ((((gz << 12) + (gy << 6) + gx) << 6) + q * 8) : 0;  // ushort units
    lofs[k] = hpos * 48 + q * 16;                                        // bytes
  }

  f32x4 acc[4][8];
#pragma unroll
  for (int mf = 0; mf < 4; ++mf)
#pragma unroll
    for (int nf = 0; nf < 8; ++nf) acc[mf][nf] = (f32x4)0.f;

  const int nb0 = ((wv * 10) * 18 + ww) * 48;   // nf adds 18*48=864 per step

  for (int g = 0; g < 4; ++g) {
    __syncthreads();   // previous group's reads complete
    uint4 stg[9];
#pragma unroll
    for (int k = 0; k < 9; ++k)
      stg[k] = gok[k] ? *(const uint4*)(x1b + gofs[k] + g * 16)
                      : make_uint4(0u, 0u, 0u, 0u);
#pragma unroll
    for (int k = 0; k < 9; ++k)
      if (sval[k]) *(uint4*)(sh + lofs[k]) = stg[k];
    __syncthreads();

    for (int c = 0; c < 14; ++c) {
      // A fragments (weights) — coalesced 16B/lane from global (L2-resident)
      bf16x8 a0 = *(const bf16x8*)(wtm + ((((g * 14 + c) * 4 + 0) * 64 + lane) << 3));
      bf16x8 a1 = *(const bf16x8*)(wtm + ((((g * 14 + c) * 4 + 1) * 64 + lane) << 3));
      bf16x8 a2 = *(const bf16x8*)(wtm + ((((g * 14 + c) * 4 + 2) * 64 + lane) << 3));
      bf16x8 a3 = *(const bf16x8*)(wtm + ((((g * 14 + c) * 4 + 3) * 64 + lane) << 3));
      // B addressing: tap = 2c + (kb>>1); pad tap 27 -> clamp to 26 (weight is 0)
      int tap = 2 * c + (kb >> 1);
      int tapc = min(tap, 26);
      int kd = (tapc * 57) >> 9;
      int rem = tapc - kd * 9;
      int kh = (rem * 43) >> 7;
      int kw = rem - kh * 3;
      int rb = ((kd * 10 + kh) * 18 + kw) * 48 + (kb & 1) * 16;
      const char* bp = sh + nb0 + rb;
      bf16x8 b0 = *(const bf16x8*)(bp);
      bf16x8 b1 = *(const bf16x8*)(bp + 864);
      bf16x8 b2 = *(const bf16x8*)(bp + 2 * 864);
      bf16x8 b3 = *(const bf16x8*)(bp + 3 * 864);
      bf16x8 b4 = *(const bf16x8*)(bp + 4 * 864);
      bf16x8 b5 = *(const bf16x8*)(bp + 5 * 864);
      bf16x8 b6 = *(const bf16x8*)(bp + 6 * 864);
      bf16x8 b7 = *(const bf16x8*)(bp + 7 * 864);
#define MFMA_ROW(MF, AF)                                                              \
      acc[MF][0] = __builtin_amdgcn_mfma_f32_16x16x32_bf16(AF, b0, acc[MF][0], 0, 0, 0); \
      acc[MF][1] = __builtin_amdgcn_mfma_f32_16x16x32_bf16(AF, b1, acc[MF][1], 0, 0, 0); \
      acc[MF][2] = __builtin_amdgcn_mfma_f32_16x16x32_bf16(AF, b2, acc[MF][2], 0, 0, 0); \
      acc[MF][3] = __builtin_amdgcn_mfma_f32_16x16x32_bf16(AF, b3, acc[MF][3], 0, 0, 0); \
      acc[MF][4] = __builtin_amdgcn_mfma_f32_16x16x32_bf16(AF, b4, acc[MF][4], 0, 0, 0); \
      acc[MF][5] = __builtin_amdgcn_mfma_f32_16x16x32_bf16(AF, b5, acc[MF][5], 0, 0, 0); \
      acc[MF][6] = __builtin_amdgcn_mfma_f32_16x16x32_bf16(AF, b6, acc[MF][6], 0, 0, 0); \
      acc[MF][7] = __builtin_amdgcn_mfma_f32_16x16x32_bf16(AF, b7, acc[MF][7], 0, 0, 0);
      MFMA_ROW(0, a0)
      MFMA_ROW(1, a1)
      MFMA_ROW(2, a2)
      MFMA_ROW(3, a3)
#undef MFMA_ROW
    }
  }

  // ---- epilogue: D layout col=lane&15 (n), row m = mf*16 + (lane>>4)*4 + r ----
  const int msub = (lane >> 4) * 2;  // note: (lane>>4)*4 elsewhere; msub*2 used below
#pragma unroll
  for (int mf = 0; mf < 4; ++mf) {
#pragma unroll
    for (int nf = 0; nf < 8; ++nf) {
      int idx = ((d0 + wv) << 12) + ((h0 + nf) << 6) + (w0 + ww);
#pragma unroll
      for (int r = 0; r < 4; ++r) {
        int m = mf * 16 + (lane >> 4) * 4 + r;
        if (m < 50) {
          float v = acc[mf][nf][r];
          x2[(size_t)m * NV + idx] = (v >= 0.f) ? v : 0.01f * v;
        }
      }
    }
  }
  (void)msub;
}

// ---------------- conv3 (50 -> 1) + residual update (R1 structure) ----------------
__global__ __launch_bounds__(256) void conv3_kernel(const float* __restrict__ x2,
                                                    const float* __restrict__ w3,
                                                    float* __restrict__ residual,
                                                    float* __restrict__ resOut) {
  __shared__ float sh[600];
  int tx = threadIdx.x & 7, ty = (threadIdx.x >> 3) & 7, tz = threadIdx.x >> 6;
  int w0 = blockIdx.x * 8, h0 = blockIdx.y * 8, d0 = blockIdx.z * 4;
  float acc = 0.f;
  for (int ci = 0; ci < 50; ++ci) {
    const float* src = x2 + (size_t)ci * NV;
    STAGE_TILE(src)
    const float* wr = w3 + ci * 27;
#pragma unroll
    for (int kd = 0; kd < 3; ++kd)
#pragma unroll
      for (int kh = 0; kh < 3; ++kh)
#pragma unroll
        for (int kw = 0; kw < 3; ++kw) {
          float xv = sh[(tz + kd) * 100 + (ty + kh) * 10 + (tx + kw)];
          acc = fmaf(xv, wr[(kd * 3 + kh) * 3 + kw], acc);
        }
  }
  int idx = ((d0 + tz) << 12) + ((h0 + ty) << 6) + (w0 + tx);
  float nr = residual[idx] + acc / 10.0f;
  residual[idx] = nr;
  resOut[idx] = nr;
}

// ---------------- res_def warp + add residual ----------------
__global__ void resdef_kernel(const float* __restrict__ rdOld, const float* __restrict__ v,
                              const float* __restrict__ residual, float* __restrict__ rdNew,
                              int doSample) {
  int idx = blockIdx.x * 256 + threadIdx.x;
  float val = 0.f;
  if (doSample) {
    int p = idx >> 12, q = (idx >> 6) & 63, r = idx & 63;
    int tidx = (r << 12) + (q << 6) + p;
    const float step = 2.0f / 63.0f;
    float gx = (-1.f + r * step) - v[tidx] / 10.0f;
    float gy = (-1.f + q * step) - v[NV + tidx] / 10.0f;
    float gz = (-1.f + p * step) - v[2 * NV + tidx] / 10.0f;
    int id[8]; float wt[8];
    tl_make(gx, gy, gz, 1, 64, 4096, id, wt);
    val = tl_apply(rdOld, id, wt);
  }
  rdNew[idx] = val + residual[idx];
}

// ---------------- fused phi warp + image update ----------------
__global__ void phi_image_kernel(const float* __restrict__ v, const float* __restrict__ phiOld,
                                 float* __restrict__ phiNew, const float* __restrict__ src,
                                 const float* __restrict__ seg, const float* __restrict__ rd,
                                 float* __restrict__ image) {
  int idx = blockIdx.x * 256 + threadIdx.x;
  int d = idx >> 12, h = (idx >> 6) & 63, w = idx & 63;
  const float step = 2.0f / 63.0f;
  float gx = (-1.f + d * step) - v[idx] / 10.0f;
  float gy = (-1.f + h * step) - v[NV + idx] / 10.0f;
  float gz = (-1.f + w * step) - v[2 * NV + idx] / 10.0f;
  int id[8]; float wt[8];
  tl_make(gx, gy, gz, 4096, 64, 1, id, wt);
  float px = tl_apply(phiOld, id, wt);
  float py = tl_apply(phiOld + NV, id, wt);
  float pz = tl_apply(phiOld + 2 * NV, id, wt);
  phiNew[idx] = px;
  phiNew[NV + idx] = py;
  phiNew[2 * NV + idx] = pz;
  int id2[8]; float wt2[8];
  tl_make(px, py, pz, 1, 64, 4096, id2, wt2);
  float sval = tl_apply(src, id2, wt2);
  float mval = tl_apply(seg, id2, wt2);
  image[idx] = sval + rd[idx] * 4.0e-05f * mval;   // MU^2/L
}

// ---------------- weight prep ----------------
// wt1: [i][ci=3][tap=27][o pad 52] f32 (R1 layout)
__global__ void wt1_kernel(const float* __restrict__ W1, float* __restrict__ wt1) {
  int gid = blockIdx.x * 256 + threadIdx.x;
  if (gid >= 10 * 50 * 3 * 27) return;
  int t = gid % 27; int rest = gid / 27;
  int ci = rest % 3; rest /= 3;
  int o = rest % 50; int i = rest / 50;
  wt1[(((size_t)i * 3 + ci) * 27 + t) * 52 + o] = W1[gid];
}

// wt2m: MFMA fragment order [i][g4][c14][mf4][lane64][j8] bf16
__global__ void wt2m_kernel(const float* __restrict__ W2, unsigned short* __restrict__ wtm) {
  int gid = blockIdx.x * 256 + threadIdx.x;
  if (gid >= 10 * 4 * 14 * 4 * 64 * 8) return;
  int j = gid & 7;
  int l = (gid >> 3) & 63;
  int mf = (gid >> 9) & 3;
  int rest = gid >> 11;
  int c = rest % 14; rest /= 14;
  int g = rest & 3;  int i = rest >> 2;
  int m = mf * 16 + (l & 15);
  int kb = l >> 4;
  int klocal = c * 32 + kb * 8 + j;
  int tap = klocal >> 4;
  int cil = klocal & 15;
  int ci = g * 16 + cil;
  float v = 0.f;
  if (tap < 27 && ci < 50 && m < 50)
    v = W2[(((size_t)i * 50 + m) * 50 + ci) * 27 + tap];
  wtm[gid] = f2bf(v);
}

// ---------------- final copy ----------------
__global__ void final_copy(const float* __restrict__ image, const float* __restrict__ rd,
                           float* __restrict__ outImg, float* __restrict__ outRd) {
  int idx = blockIdx.x * 256 + threadIdx.x;
  outImg[idx] = image[idx];
  outRd[idx] = rd[idx];
}

extern "C" void kernel_launch(void* const* d_in, const int* in_sizes, int n_in,
                              void* d_out, int out_size, void* d_ws, size_t ws_size,
                              hipStream_t stream) {
  const float* src = (const float*)d_in[0];
  const float* tgt = (const float*)d_in[1];
  const float* seg = (const float*)d_in[2];
  const float* z0  = (const float*)d_in[3];
  const float* W1  = (const float*)d_in[4];
  const float* W2  = (const float*)d_in[5];
  const float* W3  = (const float*)d_in[6];
  float* out = (float*)d_out;
  float* ws = (float*)d_ws;

  const size_t N = NV;
  float* residual = ws;                      // 1
  float* image    = ws + N;                  // 1
  float* rdb[2]   = { ws + 2 * N, ws + 3 * N };
  float* phib[2]  = { ws + 4 * N, ws + 7 * N };   // 3 each
  float* vbuf     = ws + 10 * N;                  // 3
  float* t1       = ws + 13 * N;                  // 3
  float* t2       = ws + 16 * N;                  // 3
  float* x2       = ws + 19 * N;                  // 50
  unsigned short* x1b = (unsigned short*)(ws + 69 * N);   // 64N ushort = 32N f32
  float* wt1      = ws + 101 * N;                 // 42120
  unsigned short* wt2m = (unsigned short*)(ws + 101 * N + 42120);  // 1,146,880 ushort

  size_t needed = (101 * N + 42120) * sizeof(float) + (size_t)10 * 4 * 14 * 4 * 64 * 8 * 2;
  if (ws_size < needed) return;

  float* out_image  = out;
  float* out_fields = out + N;
  float* out_grads  = out + 31 * N;
  float* out_resid  = out + 61 * N;
  float* out_rd     = out + 72 * N;

  dim3 blk(256);
  dim3 grdN((unsigned)(N / 256));
  dim3 grd3((unsigned)(N / 256), 3);
  dim3 cgrd(8, 8, 16);
  dim3 mgrd(4, 8, 16);

  init_kernel<<<grdN, blk, 0, stream>>>(src, z0, residual, image, rdb[0], phib[0], out_resid);
  wt1_kernel<<<(10 * 50 * 3 * 27 + 255) / 256, blk, 0, stream>>>(W1, wt1);
  wt2m_kernel<<<(10 * 4 * 14 * 4 * 64 * 8 + 255) / 256, blk, 0, stream>>>(W2, wt2m);

  int rc = 0, pc = 0;
  for (int i = 0; i < 10; ++i) {
    grad_kernel<<<grdN, blk, 0, stream>>>(image, out_grads + (size_t)i * 3 * N);

    smooth_d_fused<<<grd3, blk, 0, stream>>>(residual, out_grads + (size_t)i * 3 * N, t1);
    smooth_axis<6><<<grd3, blk, 0, stream>>>(t1, t2);
    smooth_axis<0><<<grd3, blk, 0, stream>>>(t2, vbuf);

    field_def_kernel<<<grdN, blk, 0, stream>>>(vbuf, out_fields + (size_t)i * 3 * N);

    conv1_kernel<<<cgrd, blk, 0, stream>>>(residual, image, tgt,
                                           wt1 + (size_t)i * 3 * 27 * 52, x1b);
    conv2_mfma<<<mgrd, blk, 0, stream>>>(x1b, wt2m + (size_t)i * 4 * 14 * 4 * 64 * 8, x2);
    conv3_kernel<<<cgrd, blk, 0, stream>>>(x2, W3 + (size_t)i * 1350, residual,
                                           out_resid + (size_t)(i + 1) * N);

    resdef_kernel<<<grdN, blk, 0, stream>>>(rdb[rc], vbuf, residual, rdb[1 - rc],
                                            i > 0 ? 1 : 0);
    rc = 1 - rc;

    phi_image_kernel<<<grdN, blk, 0, stream>>>(vbuf, phib[pc], phib[1 - pc], src, seg,
                                               rdb[rc], image);
    pc = 1 - pc;
  }

  final_copy<<<grdN, blk, 0, stream>>>(image, rdb[rc], out_image, out_rd);
}

// Round 5
// 2419.133 us; speedup vs baseline: 19.4844x; 1.2350x over previous
//
#include <hip/hip_runtime.h>

#define NV 262144          // 64^3

using bf16x8 = __attribute__((ext_vector_type(8))) short;
using f32x4  = __attribute__((ext_vector_type(4))) float;

static __device__ __forceinline__ unsigned short f2bf(float x) {
  unsigned int u = __float_as_uint(x);
  unsigned int r = (u + 0x7FFFu + ((u >> 16) & 1u)) >> 16;
  return (unsigned short)r;
}

// ---------------- Gaussian weights (13-tap, sigma=2) ----------------
static __device__ __forceinline__ void gauss_weights(float K[13]) {
  float s = 0.f;
#pragma unroll
  for (int j = 0; j < 13; ++j) {
    float r = (float)(j - 6);
    K[j] = expf(-0.125f * r * r);
    s += K[j];
  }
#pragma unroll
  for (int j = 0; j < 13; ++j) K[j] = K[j] / s;
}

// ---------------- trilinear helpers ----------------
static __device__ __forceinline__ void tl_make(float gx, float gy, float gz,
                                               int sx, int sy, int sz,
                                               int id[8], float wt[8]) {
  float x = fminf(fmaxf((gx + 1.0f) * 0.5f * 63.0f, 0.0f), 63.0f);
  float y = fminf(fmaxf((gy + 1.0f) * 0.5f * 63.0f, 0.0f), 63.0f);
  float z = fminf(fmaxf((gz + 1.0f) * 0.5f * 63.0f, 0.0f), 63.0f);
  float x0f = floorf(x), y0f = floorf(y), z0f = floorf(z);
  int x0 = (int)x0f, y0 = (int)y0f, z0 = (int)z0f;
  int x1 = min(x0 + 1, 63), y1 = min(y0 + 1, 63), z1 = min(z0 + 1, 63);
  float wx = x - x0f, wy = y - y0f, wz = z - z0f;
  float ux = 1.f - wx, uy = 1.f - wy, uz = 1.f - wz;
  int X0 = x0 * sx, X1 = x1 * sx, Y0 = y0 * sy, Y1 = y1 * sy, Z0 = z0 * sz, Z1 = z1 * sz;
  id[0] = Z0 + Y0 + X0; wt[0] = uz * uy * ux;
  id[1] = Z0 + Y0 + X1; wt[1] = uz * uy * wx;
  id[2] = Z0 + Y1 + X0; wt[2] = uz * wy * ux;
  id[3] = Z0 + Y1 + X1; wt[3] = uz * wy * wx;
  id[4] = Z1 + Y0 + X0; wt[4] = wz * uy * ux;
  id[5] = Z1 + Y0 + X1; wt[5] = wz * uy * wx;
  id[6] = Z1 + Y1 + X0; wt[6] = wz * wy * ux;
  id[7] = Z1 + Y1 + X1; wt[7] = wz * wy * wx;
}

static __device__ __forceinline__ float tl_apply(const float* __restrict__ img,
                                                 const int id[8], const float wt[8]) {
  float s = 0.f;
#pragma unroll
  for (int k = 0; k < 8; ++k) s = fmaf(wt[k], img[id[k]], s);
  return s;
}

// ---------------- init ----------------
__global__ void init_kernel(const float* __restrict__ src, const float* __restrict__ z0,
                            float* __restrict__ residual, float* __restrict__ image,
                            float* __restrict__ rd0, float* __restrict__ phi0,
                            float* __restrict__ outRes0) {
  int idx = blockIdx.x * 256 + threadIdx.x;
  int d = idx >> 12, h = (idx >> 6) & 63, w = idx & 63;
  float z = z0[idx];
  residual[idx] = z;
  outRes0[idx] = z;
  image[idx] = src[idx];
  rd0[idx] = 0.f;
  const float step = 2.0f / 63.0f;
  phi0[idx] = -1.f + w * step;
  phi0[NV + idx] = -1.f + h * step;
  phi0[2 * NV + idx] = -1.f + d * step;
}

// ---------------- spatial gradient ----------------
__global__ void grad_kernel(const float* __restrict__ img, float* __restrict__ gout) {
  int idx = blockIdx.x * 256 + threadIdx.x;
  int d = idx >> 12, h = (idx >> 6) & 63, w = idx & 63;
  int wp = min(w + 1, 63), wm = max(w - 1, 0);
  int hp = min(h + 1, 63), hm = max(h - 1, 0);
  int dp = min(d + 1, 63), dm = max(d - 1, 0);
  int bd = d << 12, bh = h << 6;
  gout[idx]          = 0.5f * (img[bd + bh + wp] - img[bd + bh + wm]);
  gout[NV + idx]     = 0.5f * (img[bd + (hp << 6) + w] - img[bd + (hm << 6) + w]);
  gout[2 * NV + idx] = 0.5f * (img[(dp << 12) + bh + w] - img[(dm << 12) + bh + w]);
}

// ---------------- Gaussian smoothing ----------------
__global__ void smooth_d_fused(const float* __restrict__ residual, const float* __restrict__ g,
                               float* __restrict__ out) {
  int idx = blockIdx.x * 256 + threadIdx.x;
  int c = blockIdx.y;
  int d = idx >> 12;
  float K[13]; gauss_weights(K);
  const float* gc = g + (size_t)c * NV;
  float acc = 0.f;
#pragma unroll
  for (int j = 0; j < 13; ++j) {
    int dd = d + j - 6;
    if ((unsigned)dd < 64u) {
      int o = idx + ((j - 6) << 12);
      acc = fmaf(K[j], -residual[o] * gc[o], acc);
    }
  }
  out[(size_t)c * NV + idx] = acc;
}

template <int SHIFT>
__global__ void smooth_axis(const float* __restrict__ in, float* __restrict__ out) {
  int idx = blockIdx.x * 256 + threadIdx.x;
  int c = blockIdx.y;
  int pos = (idx >> SHIFT) & 63;
  float K[13]; gauss_weights(K);
  const float* ic = in + (size_t)c * NV;
  float acc = 0.f;
#pragma unroll
  for (int j = 0; j < 13; ++j) {
    int pp = pos + j - 6;
    if ((unsigned)pp < 64u) acc = fmaf(K[j], ic[idx + ((j - 6) << SHIFT)], acc);
  }
  out[(size_t)c * NV + idx] = acc;
}

// ---------------- fields output ----------------
__global__ void field_def_kernel(const float* __restrict__ v, float* __restrict__ fout) {
  int idx = blockIdx.x * 256 + threadIdx.x;
  int p = idx >> 12, q = (idx >> 6) & 63, r = idx & 63;
  int tidx = (r << 12) + (q << 6) + p;
  fout[idx * 3 + 0] = v[tidx];
  fout[idx * 3 + 1] = v[NV + tidx];
  fout[idx * 3 + 2] = v[2 * NV + tidx];
}

// ---------------- conv staging macro (R1-proven, f32) ----------------
#define STAGE_TILE(SRCPTR)                                                        \
  __syncthreads();                                                                \
  for (int s = threadIdx.x; s < 600; s += 256) {                                  \
    int lz = s / 100; int r2 = s - lz * 100; int ly = r2 / 10; int lx = r2 - ly * 10; \
    int gz = d0 + lz - 1, gy = h0 + ly - 1, gx = w0 + lx - 1;                     \
    float val = 0.f;                                                              \
    if ((unsigned)gz < 64u && (unsigned)gy < 64u && (unsigned)gx < 64u)           \
      val = (SRCPTR)[(gz << 12) + (gy << 6) + gx];                                \
    sh[s] = val;                                                                  \
  }                                                                               \
  __syncthreads();

// ---------------- conv1: 3 -> 50, R1 structure, bf16 channel-last output ----------------
__global__ __launch_bounds__(256) void conv1_kernel(const float* __restrict__ zin,
                                                    const float* __restrict__ img,
                                                    const float* __restrict__ tgt,
                                                    const float* __restrict__ wt,
                                                    unsigned short* __restrict__ x1b) {
  __shared__ float sh[600];
  int tx = threadIdx.x & 7, ty = (threadIdx.x >> 3) & 7, tz = threadIdx.x >> 6;
  int w0 = blockIdx.x * 8, h0 = blockIdx.y * 8, d0 = blockIdx.z * 4;
  float acc[50];
#pragma unroll
  for (int o = 0; o < 50; ++o) acc[o] = 0.f;
  for (int ci = 0; ci < 3; ++ci) {
    const float* src = (ci == 0) ? zin : (ci == 1 ? img : tgt);
    STAGE_TILE(src)
    const float* wci = wt + ci * 27 * 52;
#pragma unroll
    for (int kd = 0; kd < 3; ++kd)
#pragma unroll
      for (int kh = 0; kh < 3; ++kh)
#pragma unroll
        for (int kw = 0; kw < 3; ++kw) {
          float xv = sh[(tz + kd) * 100 + (ty + kh) * 10 + (tx + kw)];
          const float* wrow = wci + ((kd * 3 + kh) * 3 + kw) * 52;
#pragma unroll
          for (int o = 0; o < 50; ++o) acc[o] = fmaf(xv, wrow[o], acc[o]);
        }
  }
  int idx = ((d0 + tz) << 12) + ((h0 + ty) << 6) + (w0 + tx);
  unsigned int base = (unsigned int)idx * 64u;
#pragma unroll
  for (int o = 0; o < 64; o += 2) {
    float v0 = 0.f, v1 = 0.f;
    if (o < 50)     { float a = acc[o];     v0 = (a >= 0.f) ? a : 0.01f * a; }
    if (o + 1 < 50) { float a = acc[o + 1]; v1 = (a >= 0.f) ? a : 0.01f * a; }
    unsigned int pk = (unsigned int)f2bf(v0) | ((unsigned int)f2bf(v1) << 16);
    *(unsigned int*)(x1b + base + o) = pk;
  }
}

// ---------------- MFMA staging (channel-last bf16, tile 16x4x4, halo 18x6x6) ----------------
#define MFMA_PREP(XB)                                                              \
  int gofs[6]; int lofs[6]; bool gok[6]; bool sval[6];                             \
  _Pragma("unroll")                                                                \
  for (int k = 0; k < 6; ++k) {                                                    \
    int s = tid + k * 256;                                                         \
    sval[k] = (s < 1296);                                                          \
    int hpos = s >> 1, q = s & 1;                                                  \
    int wws = hpos % 18; int rest = hpos / 18;                                     \
    int hh = rest % 6;   int dd = rest / 6;                                        \
    int gz = d0 + dd - 1, gy = h0 + hh - 1, gx = w0 + wws - 1;                     \
    bool ok = sval[k] && ((unsigned)gz < 64u) && ((unsigned)gy < 64u) && ((unsigned)gx < 64u); \
    gok[k] = ok;                                                                   \
    gofs[k] = ok ? ((((gz << 12) + (gy << 6) + gx) << 6) + q * 8) : 0;             \
    lofs[k] = hpos * 48 + q * 16;                                                  \
  }

#define MFMA_STAGE(XB, G)                                                          \
  __syncthreads();                                                                 \
  {                                                                                \
    uint4 stg[6];                                                                  \
    _Pragma("unroll")                                                              \
    for (int k = 0; k < 6; ++k)                                                    \
      stg[k] = gok[k] ? *(const uint4*)((XB) + gofs[k] + (G) * 16)                 \
                      : make_uint4(0u, 0u, 0u, 0u);                                \
    _Pragma("unroll")                                                              \
    for (int k = 0; k < 6; ++k)                                                    \
      if (sval[k]) *(uint4*)(sh + lofs[k]) = stg[k];                               \
  }                                                                                \
  __syncthreads();

#define TAP_ADDR                                                                   \
  int tap = 2 * c + (kb >> 1);                                                     \
  int tapc = min(tap, 26);                                                         \
  int kd = (tapc * 57) >> 9;                                                       \
  int rem = tapc - kd * 9;                                                         \
  int kh = (rem * 43) >> 7;                                                        \
  int kw = rem - kh * 3;                                                           \
  int rb = ((kd * 6 + kh) * 18 + kw) * 48 + (kb & 1) * 16;

// ---------------- conv2: MFMA implicit GEMM (50->50), channel-last bf16 in/out ----------------
__global__ __launch_bounds__(256) void conv2_mfma(const unsigned short* __restrict__ x1b,
                                                  const unsigned short* __restrict__ wtm,
                                                  unsigned short* __restrict__ x2b) {
  __shared__ char sh[648 * 48];
  const int tid = threadIdx.x;
  const int lane = tid & 63;
  const int wv = tid >> 6;          // wave id = d_local (0..3)
  const int ww = lane & 15;         // spatial w within fragment
  const int kb = lane >> 4;         // k sub-block (0..3)
  const int w0 = blockIdx.x * 16, h0 = blockIdx.y * 4, d0 = blockIdx.z * 4;

  MFMA_PREP(x1b)

  f32x4 acc[4][4];
#pragma unroll
  for (int mf = 0; mf < 4; ++mf)
#pragma unroll
    for (int nf = 0; nf < 4; ++nf) acc[mf][nf] = (f32x4)0.f;

  const int nb0 = (wv * 108 + ww) * 48;

  for (int g = 0; g < 4; ++g) {
    MFMA_STAGE(x1b, g)
    for (int c = 0; c < 14; ++c) {
      bf16x8 a0 = *(const bf16x8*)(wtm + ((((g * 14 + c) * 4 + 0) * 64 + lane) << 3));
      bf16x8 a1 = *(const bf16x8*)(wtm + ((((g * 14 + c) * 4 + 1) * 64 + lane) << 3));
      bf16x8 a2 = *(const bf16x8*)(wtm + ((((g * 14 + c) * 4 + 2) * 64 + lane) << 3));
      bf16x8 a3 = *(const bf16x8*)(wtm + ((((g * 14 + c) * 4 + 3) * 64 + lane) << 3));
      TAP_ADDR
      const char* bp = sh + nb0 + rb;
      bf16x8 b0 = *(const bf16x8*)(bp);
      bf16x8 b1 = *(const bf16x8*)(bp + 864);
      bf16x8 b2 = *(const bf16x8*)(bp + 2 * 864);
      bf16x8 b3 = *(const bf16x8*)(bp + 3 * 864);
#define MFMA_ROW(MF, AF)                                                              \
      acc[MF][0] = __builtin_amdgcn_mfma_f32_16x16x32_bf16(AF, b0, acc[MF][0], 0, 0, 0); \
      acc[MF][1] = __builtin_amdgcn_mfma_f32_16x16x32_bf16(AF, b1, acc[MF][1], 0, 0, 0); \
      acc[MF][2] = __builtin_amdgcn_mfma_f32_16x16x32_bf16(AF, b2, acc[MF][2], 0, 0, 0); \
      acc[MF][3] = __builtin_amdgcn_mfma_f32_16x16x32_bf16(AF, b3, acc[MF][3], 0, 0, 0);
      MFMA_ROW(0, a0)
      MFMA_ROW(1, a1)
      MFMA_ROW(2, a2)
      MFMA_ROW(3, a3)
#undef MFMA_ROW
    }
  }

  // epilogue: m = mf*16 + kb*4 + r, n = ww; write channel-last bf16 [idx][64]
#pragma unroll
  for (int nf = 0; nf < 4; ++nf) {
    int idx = ((d0 + wv) << 12) + ((h0 + nf) << 6) + (w0 + ww);
    unsigned int base = (unsigned int)idx * 64u + kb * 4u;
#pragma unroll
    for (int mf = 0; mf < 4; ++mf) {
      float v0 = acc[mf][nf][0], v1 = acc[mf][nf][1];
      float v2 = acc[mf][nf][2], v3 = acc[mf][nf][3];
      v0 = (v0 >= 0.f) ? v0 : 0.01f * v0;
      v1 = (v1 >= 0.f) ? v1 : 0.01f * v1;
      v2 = (v2 >= 0.f) ? v2 : 0.01f * v2;
      v3 = (v3 >= 0.f) ? v3 : 0.01f * v3;
      unsigned int u0 = (unsigned int)f2bf(v0) | ((unsigned int)f2bf(v1) << 16);
      unsigned int u1 = (unsigned int)f2bf(v2) | ((unsigned int)f2bf(v3) << 16);
      *(uint2*)(x2b + base + mf * 16u) = make_uint2(u0, u1);
    }
  }
}

// ---------------- conv3: MFMA (50->1, M=16 with m=0 live) + residual update ----------------
__global__ __launch_bounds__(256) void conv3_mfma(const unsigned short* __restrict__ x2b,
                                                  const unsigned short* __restrict__ w3m,
                                                  float* __restrict__ residual,
                                                  float* __restrict__ resOut) {
  __shared__ char sh[648 * 48];
  const int tid = threadIdx.x;
  const int lane = tid & 63;
  const int wv = tid >> 6;
  const int ww = lane & 15;
  const int kb = lane >> 4;
  const int w0 = blockIdx.x * 16, h0 = blockIdx.y * 4, d0 = blockIdx.z * 4;

  MFMA_PREP(x2b)

  f32x4 acc[4];
#pragma unroll
  for (int nf = 0; nf < 4; ++nf) acc[nf] = (f32x4)0.f;

  const int nb0 = (wv * 108 + ww) * 48;

  for (int g = 0; g < 4; ++g) {
    MFMA_STAGE(x2b, g)
    for (int c = 0; c < 14; ++c) {
      bf16x8 a0 = *(const bf16x8*)(w3m + (((g * 14 + c) * 64 + lane) << 3));
      TAP_ADDR
      const char* bp = sh + nb0 + rb;
      bf16x8 b0 = *(const bf16x8*)(bp);
      bf16x8 b1 = *(const bf16x8*)(bp + 864);
      bf16x8 b2 = *(const bf16x8*)(bp + 2 * 864);
      bf16x8 b3 = *(const bf16x8*)(bp + 3 * 864);
      acc[0] = __builtin_amdgcn_mfma_f32_16x16x32_bf16(a0, b0, acc[0], 0, 0, 0);
      acc[1] = __builtin_amdgcn_mfma_f32_16x16x32_bf16(a0, b1, acc[1], 0, 0, 0);
      acc[2] = __builtin_amdgcn_mfma_f32_16x16x32_bf16(a0, b2, acc[2], 0, 0, 0);
      acc[3] = __builtin_amdgcn_mfma_f32_16x16x32_bf16(a0, b3, acc[3], 0, 0, 0);
    }
  }

  // only m==0 (kb==0, r==0) is the real output
  if (lane < 16) {
#pragma unroll
    for (int nf = 0; nf < 4; ++nf) {
      int idx = ((d0 + wv) << 12) + ((h0 + nf) << 6) + (w0 + ww);
      float nr = residual[idx] + acc[nf][0] * 0.1f;
      residual[idx] = nr;
      resOut[idx] = nr;
    }
  }
}

// ---------------- fused res_def warp + phi warp + image update ----------------
__global__ void rp_fused_kernel(const float* __restrict__ rdOld, const float* __restrict__ v,
                                const float* __restrict__ residual,
                                const float* __restrict__ phiOld, float* __restrict__ phiNew,
                                const float* __restrict__ src, const float* __restrict__ seg,
                                float* __restrict__ rdNew, float* __restrict__ image,
                                int doSample) {
  int idx = blockIdx.x * 256 + threadIdx.x;
  int d = idx >> 12, h = (idx >> 6) & 63, w = idx & 63;
  const float step = 2.0f / 63.0f;

  // res_def warp (reads v transposed)
  float val = 0.f;
  if (doSample) {
    int tidx = (w << 12) + (h << 6) + d;
    float gx = (-1.f + w * step) - v[tidx] / 10.0f;
    float gy = (-1.f + h * step) - v[NV + tidx] / 10.0f;
    float gz = (-1.f + d * step) - v[2 * NV + tidx] / 10.0f;
    int id[8]; float wt[8];
    tl_make(gx, gy, gz, 1, 64, 4096, id, wt);
    val = tl_apply(rdOld, id, wt);
  }
  float nr = val + residual[idx];
  rdNew[idx] = nr;

  // phi warp
  float gx = (-1.f + d * step) - v[idx] / 10.0f;
  float gy = (-1.f + h * step) - v[NV + idx] / 10.0f;
  float gz = (-1.f + w * step) - v[2 * NV + idx] / 10.0f;
  int id[8]; float wt[8];
  tl_make(gx, gy, gz, 4096, 64, 1, id, wt);
  float px = tl_apply(phiOld, id, wt);
  float py = tl_apply(phiOld + NV, id, wt);
  float pz = tl_apply(phiOld + 2 * NV, id, wt);
  phiNew[idx] = px;
  phiNew[NV + idx] = py;
  phiNew[2 * NV + idx] = pz;

  // image update
  int id2[8]; float wt2[8];
  tl_make(px, py, pz, 1, 64, 4096, id2, wt2);
  float sval = tl_apply(src, id2, wt2);
  float mval = tl_apply(seg, id2, wt2);
  image[idx] = sval + nr * 4.0e-05f * mval;   // MU^2/L
}

// ---------------- weight prep ----------------
// wt1: [i][ci=3][tap=27][o pad 52] f32
__global__ void wt1_kernel(const float* __restrict__ W1, float* __restrict__ wt1) {
  int gid = blockIdx.x * 256 + threadIdx.x;
  if (gid >= 10 * 50 * 3 * 27) return;
  int t = gid % 27; int rest = gid / 27;
  int ci = rest % 3; rest /= 3;
  int o = rest % 50; int i = rest / 50;
  wt1[(((size_t)i * 3 + ci) * 27 + t) * 52 + o] = W1[gid];
}

// wt2m: MFMA fragment order [i][g4][c14][mf4][lane64][j8] bf16
__global__ void wt2m_kernel(const float* __restrict__ W2, unsigned short* __restrict__ wtm) {
  int gid = blockIdx.x * 256 + threadIdx.x;
  if (gid >= 10 * 4 * 14 * 4 * 64 * 8) return;
  int j = gid & 7;
  int l = (gid >> 3) & 63;
  int mf = (gid >> 9) & 3;
  int rest = gid >> 11;
  int c = rest % 14; rest /= 14;
  int g = rest & 3;  int i = rest >> 2;
  int m = mf * 16 + (l & 15);
  int kb = l >> 4;
  int klocal = c * 32 + kb * 8 + j;
  int tap = klocal >> 4;
  int cil = klocal & 15;
  int ci = g * 16 + cil;
  float v = 0.f;
  if (tap < 27 && ci < 50 && m < 50)
    v = W2[(((size_t)i * 50 + m) * 50 + ci) * 27 + tap];
  wtm[gid] = f2bf(v);
}

// w3m: [i][g4][c14][lane64][j8] bf16, only m==0 rows nonzero
__global__ void w3m_kernel(const float* __restrict__ W3, unsigned short* __restrict__ w3m) {
  int gid = blockIdx.x * 256 + threadIdx.x;
  if (gid >= 10 * 4 * 14 * 64 * 8) return;
  int j = gid & 7;
  int l = (gid >> 3) & 63;
  int rest = gid >> 9;
  int c = rest % 14; rest /= 14;
  int g = rest & 3;  int i = rest >> 2;
  int m = l & 15;
  int kb = l >> 4;
  int klocal = c * 32 + kb * 8 + j;
  int tap = klocal >> 4;
  int cil = klocal & 15;
  int ci = g * 16 + cil;
  float v = 0.f;
  if (m == 0 && tap < 27 && ci < 50)
    v = W3[((size_t)i * 50 + ci) * 27 + tap];
  w3m[gid] = f2bf(v);
}

// ---------------- final copy ----------------
__global__ void final_copy(const float* __restrict__ image, const float* __restrict__ rd,
                           float* __restrict__ outImg, float* __restrict__ outRd) {
  int idx = blockIdx.x * 256 + threadIdx.x;
  outImg[idx] = image[idx];
  outRd[idx] = rd[idx];
}

extern "C" void kernel_launch(void* const* d_in, const int* in_sizes, int n_in,
                              void* d_out, int out_size, void* d_ws, size_t ws_size,
                              hipStream_t stream) {
  const float* src = (const float*)d_in[0];
  const float* tgt = (const float*)d_in[1];
  const float* seg = (const float*)d_in[2];
  const float* z0  = (const float*)d_in[3];
  const float* W1  = (const float*)d_in[4];
  const float* W2  = (const float*)d_in[5];
  const float* W3  = (const float*)d_in[6];
  float* out = (float*)d_out;
  float* ws = (float*)d_ws;

  const size_t N = NV;
  float* residual = ws;                       // 1
  float* image    = ws + N;                   // 1
  float* rdb[2]   = { ws + 2 * N, ws + 3 * N };
  float* phib[2]  = { ws + 4 * N, ws + 7 * N };   // 3 each
  float* vbuf     = ws + 10 * N;                  // 3
  float* t1       = ws + 13 * N;                  // 3
  float* t2       = ws + 16 * N;                  // 3
  unsigned short* x1b = (unsigned short*)(ws + 19 * N);   // 64N ushort = 32N f32
  unsigned short* x2b = (unsigned short*)(ws + 51 * N);   // 64N ushort = 32N f32
  float* wt1      = ws + 83 * N;                  // 42120 f32
  unsigned short* wt2m = (unsigned short*)(wt1 + 42120);            // 1,146,880 ush
  unsigned short* w3m  = wt2m + (size_t)10 * 4 * 14 * 4 * 64 * 8;   // 286,720 ush

  size_t needed = (83 * N + 42120) * sizeof(float)
                + ((size_t)10 * 4 * 14 * 4 * 64 * 8 + (size_t)10 * 4 * 14 * 64 * 8) * 2;
  if (ws_size < needed) return;

  float* out_image  = out;
  float* out_fields = out + N;
  float* out_grads  = out + 31 * N;
  float* out_resid  = out + 61 * N;
  float* out_rd     = out + 72 * N;

  dim3 blk(256);
  dim3 grdN((unsigned)(N / 256));
  dim3 grd3((unsigned)(N / 256), 3);
  dim3 cgrd(8, 8, 16);
  dim3 mgrd(4, 16, 16);

  init_kernel<<<grdN, blk, 0, stream>>>(src, z0, residual, image, rdb[0], phib[0], out_resid);
  wt1_kernel<<<(10 * 50 * 3 * 27 + 255) / 256, blk, 0, stream>>>(W1, wt1);
  wt2m_kernel<<<(10 * 4 * 14 * 4 * 64 * 8 + 255) / 256, blk, 0, stream>>>(W2, wt2m);
  w3m_kernel<<<(10 * 4 * 14 * 64 * 8 + 255) / 256, blk, 0, stream>>>(W3, w3m);

  int rc = 0, pc = 0;
  for (int i = 0; i < 10; ++i) {
    grad_kernel<<<grdN, blk, 0, stream>>>(image, out_grads + (size_t)i * 3 * N);

    smooth_d_fused<<<grd3, blk, 0, stream>>>(residual, out_grads + (size_t)i * 3 * N, t1);
    smooth_axis<6><<<grd3, blk, 0, stream>>>(t1, t2);
    smooth_axis<0><<<grd3, blk, 0, stream>>>(t2, vbuf);

    field_def_kernel<<<grdN, blk, 0, stream>>>(vbuf, out_fields + (size_t)i * 3 * N);

    conv1_kernel<<<cgrd, blk, 0, stream>>>(residual, image, tgt,
                                           wt1 + (size_t)i * 3 * 27 * 52, x1b);
    conv2_mfma<<<mgrd, blk, 0, stream>>>(x1b, wt2m + (size_t)i * 4 * 14 * 4 * 64 * 8, x2b);
    conv3_mfma<<<mgrd, blk, 0, stream>>>(x2b, w3m + (size_t)i * 4 * 14 * 64 * 8, residual,
                                         out_resid + (size_t)(i + 1) * N);

    rp_fused_kernel<<<grdN, blk, 0, stream>>>(rdb[rc], vbuf, residual, phib[pc],
                                              phib[1 - pc], src, seg, rdb[1 - rc], image,
                                              i > 0 ? 1 : 0);
    rc = 1 - rc;
    pc = 1 - pc;
  }

  final_copy<<<grdN, blk, 0, stream>>>(image, rdb[rc], out_image, out_rd);
}

// Round 6
// 2321.660 us; speedup vs baseline: 20.3024x; 1.0420x over previous
//
#include <hip/hip_runtime.h>

#define NV 262144          // 64^3

using bf16x8 = __attribute__((ext_vector_type(8))) short;
using f32x4  = __attribute__((ext_vector_type(4))) float;

static __device__ __forceinline__ unsigned short f2bf(float x) {
  unsigned int u = __float_as_uint(x);
  unsigned int r = (u + 0x7FFFu + ((u >> 16) & 1u)) >> 16;
  return (unsigned short)r;
}

// ---------------- Gaussian weights (13-tap, sigma=2) ----------------
static __device__ __forceinline__ void gauss_weights(float K[13]) {
  float s = 0.f;
#pragma unroll
  for (int j = 0; j < 13; ++j) {
    float r = (float)(j - 6);
    K[j] = expf(-0.125f * r * r);
    s += K[j];
  }
#pragma unroll
  for (int j = 0; j < 13; ++j) K[j] = K[j] / s;
}

// ---------------- trilinear helpers ----------------
static __device__ __forceinline__ void tl_make(float gx, float gy, float gz,
                                               int sx, int sy, int sz,
                                               int id[8], float wt[8]) {
  float x = fminf(fmaxf((gx + 1.0f) * 0.5f * 63.0f, 0.0f), 63.0f);
  float y = fminf(fmaxf((gy + 1.0f) * 0.5f * 63.0f, 0.0f), 63.0f);
  float z = fminf(fmaxf((gz + 1.0f) * 0.5f * 63.0f, 0.0f), 63.0f);
  float x0f = floorf(x), y0f = floorf(y), z0f = floorf(z);
  int x0 = (int)x0f, y0 = (int)y0f, z0 = (int)z0f;
  int x1 = min(x0 + 1, 63), y1 = min(y0 + 1, 63), z1 = min(z0 + 1, 63);
  float wx = x - x0f, wy = y - y0f, wz = z - z0f;
  float ux = 1.f - wx, uy = 1.f - wy, uz = 1.f - wz;
  int X0 = x0 * sx, X1 = x1 * sx, Y0 = y0 * sy, Y1 = y1 * sy, Z0 = z0 * sz, Z1 = z1 * sz;
  id[0] = Z0 + Y0 + X0; wt[0] = uz * uy * ux;
  id[1] = Z0 + Y0 + X1; wt[1] = uz * uy * wx;
  id[2] = Z0 + Y1 + X0; wt[2] = uz * wy * ux;
  id[3] = Z0 + Y1 + X1; wt[3] = uz * wy * wx;
  id[4] = Z1 + Y0 + X0; wt[4] = wz * uy * ux;
  id[5] = Z1 + Y0 + X1; wt[5] = wz * uy * wx;
  id[6] = Z1 + Y1 + X0; wt[6] = wz * wy * ux;
  id[7] = Z1 + Y1 + X1; wt[7] = wz * wy * wx;
}

static __device__ __forceinline__ float tl_apply(const float* __restrict__ img,
                                                 const int id[8], const float wt[8]) {
  float s = 0.f;
#pragma unroll
  for (int k = 0; k < 8; ++k) s = fmaf(wt[k], img[id[k]], s);
  return s;
}

// ---------------- init ----------------
__global__ void init_kernel(const float* __restrict__ src, const float* __restrict__ z0,
                            float* __restrict__ residual, float* __restrict__ image,
                            float* __restrict__ rd0, float* __restrict__ phi0,
                            float* __restrict__ outRes0) {
  int idx = blockIdx.x * 256 + threadIdx.x;
  int d = idx >> 12, h = (idx >> 6) & 63, w = idx & 63;
  float z = z0[idx];
  residual[idx] = z;
  outRes0[idx] = z;
  image[idx] = src[idx];
  rd0[idx] = 0.f;
  const float step = 2.0f / 63.0f;
  phi0[idx] = -1.f + w * step;
  phi0[NV + idx] = -1.f + h * step;
  phi0[2 * NV + idx] = -1.f + d * step;
}

// ---------------- fused gradient + smooth-D pass (+ grads output at j==6) ----------------
__global__ void gsd_kernel(const float* __restrict__ img, const float* __restrict__ residual,
                           float* __restrict__ gout, float* __restrict__ t1) {
  int idx = blockIdx.x * 256 + threadIdx.x;
  int d = idx >> 12, h = (idx >> 6) & 63, w = idx & 63;
  float K[13]; gauss_weights(K);
  int wp = min(w + 1, 63), wm = max(w - 1, 0);
  int hp = min(h + 1, 63), hm = max(h - 1, 0);
  float a0 = 0.f, a1 = 0.f, a2 = 0.f;
#pragma unroll
  for (int j = 0; j < 13; ++j) {
    int dd = d + j - 6;
    if ((unsigned)dd < 64u) {
      int b = (dd << 12) + (h << 6);
      int dp = min(dd + 1, 63), dm = max(dd - 1, 0);
      float gx = 0.5f * (img[b + wp] - img[b + wm]);
      float gy = 0.5f * (img[(dd << 12) + (hp << 6) + w] - img[(dd << 12) + (hm << 6) + w]);
      float gz = 0.5f * (img[(dp << 12) + (h << 6) + w] - img[(dm << 12) + (h << 6) + w]);
      float r = residual[b + w];
      if (j == 6) {
        gout[idx] = gx; gout[NV + idx] = gy; gout[2 * NV + idx] = gz;
      }
      a0 = fmaf(K[j], -r * gx, a0);
      a1 = fmaf(K[j], -r * gy, a1);
      a2 = fmaf(K[j], -r * gz, a2);
    }
  }
  t1[idx] = a0; t1[NV + idx] = a1; t1[2 * NV + idx] = a2;
}

// ---------------- fused smooth-H + smooth-W + fields output ----------------
// grid (16 h-tiles, 64 d); block 256 = w64 x h4; both passes in LDS.
__global__ __launch_bounds__(256) void smooth_hw(const float* __restrict__ t1,
                                                 float* __restrict__ vbuf,
                                                 float* __restrict__ fout) {
  __shared__ float shin[16][64];
  __shared__ float shh[4][64];
  int w = threadIdx.x & 63;
  int ty = threadIdx.x >> 6;
  int h0 = blockIdx.x * 4;
  int d  = blockIdx.y;
  float K[13]; gauss_weights(K);
  for (int c = 0; c < 3; ++c) {
    __syncthreads();
    const float* tc = t1 + (size_t)c * NV + (d << 12);
    for (int r = ty; r < 16; r += 4) {
      int hh = h0 - 6 + r;
      shin[r][w] = ((unsigned)hh < 64u) ? tc[(hh << 6) + w] : 0.f;
    }
    __syncthreads();
    float acc = 0.f;
#pragma unroll
    for (int j = 0; j < 13; ++j) {
      int hh = h0 + ty + j - 6;
      if ((unsigned)hh < 64u) acc = fmaf(K[j], shin[ty + j][w], acc);
    }
    shh[ty][w] = acc;
    __syncthreads();
    float o = 0.f;
#pragma unroll
    for (int j = 0; j < 13; ++j) {
      int wj = w + j - 6;
      if ((unsigned)wj < 64u) o = fmaf(K[j], shh[ty][wj], o);
    }
    int h = h0 + ty;
    vbuf[(size_t)c * NV + (d << 12) + (h << 6) + w] = o;
    // fields: out voxel (p,q,r)=(w,h,d) reads v[c] at (r,q,p)=(d,h,w)
    fout[((size_t)(w << 12) + (h << 6) + d) * 3 + c] = o;
  }
}

// ---------------- conv staging macro (R1-proven, f32) ----------------
#define STAGE_TILE(SRCPTR)                                                        \
  __syncthreads();                                                                \
  for (int s = threadIdx.x; s < 600; s += 256) {                                  \
    int lz = s / 100; int r2 = s - lz * 100; int ly = r2 / 10; int lx = r2 - ly * 10; \
    int gz = d0 + lz - 1, gy = h0 + ly - 1, gx = w0 + lx - 1;                     \
    float val = 0.f;                                                              \
    if ((unsigned)gz < 64u && (unsigned)gy < 64u && (unsigned)gx < 64u)           \
      val = (SRCPTR)[(gz << 12) + (gy << 6) + gx];                                \
    sh[s] = val;                                                                  \
  }                                                                               \
  __syncthreads();

// ---------------- conv1: 3 -> 50, R1 structure, bf16 channel-last output ----------------
__global__ __launch_bounds__(256) void conv1_kernel(const float* __restrict__ zin,
                                                    const float* __restrict__ img,
                                                    const float* __restrict__ tgt,
                                                    const float* __restrict__ wt,
                                                    unsigned short* __restrict__ x1b) {
  __shared__ float sh[600];
  int tx = threadIdx.x & 7, ty = (threadIdx.x >> 3) & 7, tz = threadIdx.x >> 6;
  int w0 = blockIdx.x * 8, h0 = blockIdx.y * 8, d0 = blockIdx.z * 4;
  float acc[50];
#pragma unroll
  for (int o = 0; o < 50; ++o) acc[o] = 0.f;
  for (int ci = 0; ci < 3; ++ci) {
    const float* src = (ci == 0) ? zin : (ci == 1 ? img : tgt);
    STAGE_TILE(src)
    const float* wci = wt + ci * 27 * 52;
#pragma unroll
    for (int kd = 0; kd < 3; ++kd)
#pragma unroll
      for (int kh = 0; kh < 3; ++kh)
#pragma unroll
        for (int kw = 0; kw < 3; ++kw) {
          float xv = sh[(tz + kd) * 100 + (ty + kh) * 10 + (tx + kw)];
          const float* wrow = wci + ((kd * 3 + kh) * 3 + kw) * 52;
#pragma unroll
          for (int o = 0; o < 50; ++o) acc[o] = fmaf(xv, wrow[o], acc[o]);
        }
  }
  int idx = ((d0 + tz) << 12) + ((h0 + ty) << 6) + (w0 + tx);
  unsigned int base = (unsigned int)idx * 64u;
#pragma unroll
  for (int o = 0; o < 64; o += 2) {
    float v0 = 0.f, v1 = 0.f;
    if (o < 50)     { float a = acc[o];     v0 = (a >= 0.f) ? a : 0.01f * a; }
    if (o + 1 < 50) { float a = acc[o + 1]; v1 = (a >= 0.f) ? a : 0.01f * a; }
    unsigned int pk = (unsigned int)f2bf(v0) | ((unsigned int)f2bf(v1) << 16);
    *(unsigned int*)(x1b + base + o) = pk;
  }
}

// ---------------- MFMA staging: tile 16x4x4, halo 18x6x6, channel-last bf16 ----------------
// LDS layout (bytes): L(dd,hh,q,wws) = ((dd*6+hh)*2+q)*288 + wws*16  -> 20736 B total.
// B-read lanes (ww 0..15) are 16B-contiguous per kb-group -> conflict-free.
#define MFMA_PREP(XB)                                                              \
  int gofs[6]; int lofs[6]; bool gok[6]; bool sval[6];                             \
  _Pragma("unroll")                                                                \
  for (int k = 0; k < 6; ++k) {                                                    \
    int s = tid + k * 256;                                                         \
    sval[k] = (s < 1296);                                                          \
    int hpos = s >> 1, q = s & 1;                                                  \
    int wws = hpos % 18; int rest = hpos / 18;                                     \
    int hh = rest % 6;   int dd = rest / 6;                                        \
    int gz = d0 + dd - 1, gy = h0 + hh - 1, gx = w0 + wws - 1;                     \
    bool ok = sval[k] && ((unsigned)gz < 64u) && ((unsigned)gy < 64u) && ((unsigned)gx < 64u); \
    gok[k] = ok;                                                                   \
    gofs[k] = ok ? ((((gz << 12) + (gy << 6) + gx) << 6) + q * 8) : 0;             \
    lofs[k] = ((dd * 6 + hh) * 2 + q) * 288 + wws * 16;                            \
  }

#define MFMA_STAGE(XB, G)                                                          \
  __syncthreads();                                                                 \
  {                                                                                \
    uint4 stg[6];                                                                  \
    _Pragma("unroll")                                                              \
    for (int k = 0; k < 6; ++k)                                                    \
      stg[k] = gok[k] ? *(const uint4*)((XB) + gofs[k] + (G) * 16)                 \
                      : make_uint4(0u, 0u, 0u, 0u);                                \
    _Pragma("unroll")                                                              \
    for (int k = 0; k < 6; ++k)                                                    \
      if (sval[k]) *(uint4*)(sh + lofs[k]) = stg[k];                               \
  }                                                                                \
  __syncthreads();

#define TAP_ADDR                                                                   \
  int tap = 2 * c + (kb >> 1);                                                     \
  int tapc = min(tap, 26);                                                         \
  int kd = (tapc * 57) >> 9;                                                       \
  int rem = tapc - kd * 9;                                                         \
  int kh = (rem * 43) >> 7;                                                        \
  int kw = rem - kh * 3;                                                           \
  int rb = ((kd * 6 + kh) * 2 + (kb & 1)) * 288 + kw * 16;

// ---------------- conv2: MFMA implicit GEMM (50->50), channel-last bf16 in/out ----------------
__global__ __launch_bounds__(256) void conv2_mfma(const unsigned short* __restrict__ x1b,
                                                  const unsigned short* __restrict__ wtm,
                                                  unsigned short* __restrict__ x2b) {
  __shared__ char sh[20736];
  const int tid = threadIdx.x;
  const int lane = tid & 63;
  const int wv = tid >> 6;          // wave id = d_local (0..3)
  const int ww = lane & 15;         // spatial w within fragment
  const int kb = lane >> 4;         // k sub-block (0..3)
  const int w0 = blockIdx.x * 16, h0 = blockIdx.y * 4, d0 = blockIdx.z * 4;

  MFMA_PREP(x1b)

  f32x4 acc[4][4];
#pragma unroll
  for (int mf = 0; mf < 4; ++mf)
#pragma unroll
    for (int nf = 0; nf < 4; ++nf) acc[mf][nf] = (f32x4)0.f;

  const int nb0 = wv * 3456 + ww * 16;   // (wv+kd) enters via rb's kd*12*288 handled relative

  for (int g = 0; g < 4; ++g) {
    MFMA_STAGE(x1b, g)
    for (int c = 0; c < 14; ++c) {
      bf16x8 a0 = *(const bf16x8*)(wtm + ((((g * 14 + c) * 4 + 0) * 64 + lane) << 3));
      bf16x8 a1 = *(const bf16x8*)(wtm + ((((g * 14 + c) * 4 + 1) * 64 + lane) << 3));
      bf16x8 a2 = *(const bf16x8*)(wtm + ((((g * 14 + c) * 4 + 2) * 64 + lane) << 3));
      bf16x8 a3 = *(const bf16x8*)(wtm + ((((g * 14 + c) * 4 + 3) * 64 + lane) << 3));
      TAP_ADDR
      const char* bp = sh + nb0 + rb;
      bf16x8 b0 = *(const bf16x8*)(bp);
      bf16x8 b1 = *(const bf16x8*)(bp + 576);
      bf16x8 b2 = *(const bf16x8*)(bp + 2 * 576);
      bf16x8 b3 = *(const bf16x8*)(bp + 3 * 576);
#define MFMA_ROW(MF, AF)                                                              \
      acc[MF][0] = __builtin_amdgcn_mfma_f32_16x16x32_bf16(AF, b0, acc[MF][0], 0, 0, 0); \
      acc[MF][1] = __builtin_amdgcn_mfma_f32_16x16x32_bf16(AF, b1, acc[MF][1], 0, 0, 0); \
      acc[MF][2] = __builtin_amdgcn_mfma_f32_16x16x32_bf16(AF, b2, acc[MF][2], 0, 0, 0); \
      acc[MF][3] = __builtin_amdgcn_mfma_f32_16x16x32_bf16(AF, b3, acc[MF][3], 0, 0, 0);
      MFMA_ROW(0, a0)
      MFMA_ROW(1, a1)
      MFMA_ROW(2, a2)
      MFMA_ROW(3, a3)
#undef MFMA_ROW
    }
  }

  // epilogue: m = mf*16 + kb*4 + r, n = ww; write channel-last bf16 [idx][64]
#pragma unroll
  for (int nf = 0; nf < 4; ++nf) {
    int idx = ((d0 + wv) << 12) + ((h0 + nf) << 6) + (w0 + ww);
    unsigned int base = (unsigned int)idx * 64u + kb * 4u;
#pragma unroll
    for (int mf = 0; mf < 4; ++mf) {
      float v0 = acc[mf][nf][0], v1 = acc[mf][nf][1];
      float v2 = acc[mf][nf][2], v3 = acc[mf][nf][3];
      v0 = (v0 >= 0.f) ? v0 : 0.01f * v0;
      v1 = (v1 >= 0.f) ? v1 : 0.01f * v1;
      v2 = (v2 >= 0.f) ? v2 : 0.01f * v2;
      v3 = (v3 >= 0.f) ? v3 : 0.01f * v3;
      unsigned int u0 = (unsigned int)f2bf(v0) | ((unsigned int)f2bf(v1) << 16);
      unsigned int u1 = (unsigned int)f2bf(v2) | ((unsigned int)f2bf(v3) << 16);
      *(uint2*)(x2b + base + mf * 16u) = make_uint2(u0, u1);
    }
  }
}

// ---------------- conv3: MFMA (50->1, m=0 live) + residual update ----------------
__global__ __launch_bounds__(256) void conv3_mfma(const unsigned short* __restrict__ x2b,
                                                  const unsigned short* __restrict__ w3m,
                                                  float* __restrict__ residual,
                                                  float* __restrict__ resOut) {
  __shared__ char sh[20736];
  const int tid = threadIdx.x;
  const int lane = tid & 63;
  const int wv = tid >> 6;
  const int ww = lane & 15;
  const int kb = lane >> 4;
  const int w0 = blockIdx.x * 16, h0 = blockIdx.y * 4, d0 = blockIdx.z * 4;

  MFMA_PREP(x2b)

  f32x4 acc[4];
#pragma unroll
  for (int nf = 0; nf < 4; ++nf) acc[nf] = (f32x4)0.f;

  const int nb0 = wv * 3456 + ww * 16;

  for (int g = 0; g < 4; ++g) {
    MFMA_STAGE(x2b, g)
    for (int c = 0; c < 14; ++c) {
      bf16x8 a0 = *(const bf16x8*)(w3m + (((g * 14 + c) * 64 + lane) << 3));
      TAP_ADDR
      const char* bp = sh + nb0 + rb;
      bf16x8 b0 = *(const bf16x8*)(bp);
      bf16x8 b1 = *(const bf16x8*)(bp + 576);
      bf16x8 b2 = *(const bf16x8*)(bp + 2 * 576);
      bf16x8 b3 = *(const bf16x8*)(bp + 3 * 576);
      acc[0] = __builtin_amdgcn_mfma_f32_16x16x32_bf16(a0, b0, acc[0], 0, 0, 0);
      acc[1] = __builtin_amdgcn_mfma_f32_16x16x32_bf16(a0, b1, acc[1], 0, 0, 0);
      acc[2] = __builtin_amdgcn_mfma_f32_16x16x32_bf16(a0, b2, acc[2], 0, 0, 0);
      acc[3] = __builtin_amdgcn_mfma_f32_16x16x32_bf16(a0, b3, acc[3], 0, 0, 0);
    }
  }

  if (lane < 16) {
#pragma unroll
    for (int nf = 0; nf < 4; ++nf) {
      int idx = ((d0 + wv) << 12) + ((h0 + nf) << 6) + (w0 + ww);
      float nr = residual[idx] + acc[nf][0] * 0.1f;
      residual[idx] = nr;
      resOut[idx] = nr;
    }
  }
}

// ---------------- fused res_def warp + phi warp + image update ----------------
__global__ void rp_fused_kernel(const float* __restrict__ rdOld, const float* __restrict__ v,
                                const float* __restrict__ residual,
                                const float* __restrict__ phiOld, float* __restrict__ phiNew,
                                const float* __restrict__ src, const float* __restrict__ seg,
                                float* __restrict__ rdNew, float* __restrict__ image,
                                int doSample) {
  int idx = blockIdx.x * 256 + threadIdx.x;
  int d = idx >> 12, h = (idx >> 6) & 63, w = idx & 63;
  const float step = 2.0f / 63.0f;

  float val = 0.f;
  if (doSample) {
    int tidx = (w << 12) + (h << 6) + d;
    float gx = (-1.f + w * step) - v[tidx] / 10.0f;
    float gy = (-1.f + h * step) - v[NV + tidx] / 10.0f;
    float gz = (-1.f + d * step) - v[2 * NV + tidx] / 10.0f;
    int id[8]; float wt[8];
    tl_make(gx, gy, gz, 1, 64, 4096, id, wt);
    val = tl_apply(rdOld, id, wt);
  }
  float nr = val + residual[idx];
  rdNew[idx] = nr;

  float gx = (-1.f + d * step) - v[idx] / 10.0f;
  float gy = (-1.f + h * step) - v[NV + idx] / 10.0f;
  float gz = (-1.f + w * step) - v[2 * NV + idx] / 10.0f;
  int id[8]; float wt[8];
  tl_make(gx, gy, gz, 4096, 64, 1, id, wt);
  float px = tl_apply(phiOld, id, wt);
  float py = tl_apply(phiOld + NV, id, wt);
  float pz = tl_apply(phiOld + 2 * NV, id, wt);
  phiNew[idx] = px;
  phiNew[NV + idx] = py;
  phiNew[2 * NV + idx] = pz;

  int id2[8]; float wt2[8];
  tl_make(px, py, pz, 1, 64, 4096, id2, wt2);
  float sval = tl_apply(src, id2, wt2);
  float mval = tl_apply(seg, id2, wt2);
  image[idx] = sval + nr * 4.0e-05f * mval;   // MU^2/L
}

// ---------------- weight prep ----------------
__global__ void wt1_kernel(const float* __restrict__ W1, float* __restrict__ wt1) {
  int gid = blockIdx.x * 256 + threadIdx.x;
  if (gid >= 10 * 50 * 3 * 27) return;
  int t = gid % 27; int rest = gid / 27;
  int ci = rest % 3; rest /= 3;
  int o = rest % 50; int i = rest / 50;
  wt1[(((size_t)i * 3 + ci) * 27 + t) * 52 + o] = W1[gid];
}

__global__ void wt2m_kernel(const float* __restrict__ W2, unsigned short* __restrict__ wtm) {
  int gid = blockIdx.x * 256 + threadIdx.x;
  if (gid >= 10 * 4 * 14 * 4 * 64 * 8) return;
  int j = gid & 7;
  int l = (gid >> 3) & 63;
  int mf = (gid >> 9) & 3;
  int rest = gid >> 11;
  int c = rest % 14; rest /= 14;
  int g = rest & 3;  int i = rest >> 2;
  int m = mf * 16 + (l & 15);
  int kb = l >> 4;
  int klocal = c * 32 + kb * 8 + j;
  int tap = klocal >> 4;
  int cil = klocal & 15;
  int ci = g * 16 + cil;
  float v = 0.f;
  if (tap < 27 && ci < 50 && m < 50)
    v = W2[(((size_t)i * 50 + m) * 50 + ci) * 27 + tap];
  wtm[gid] = f2bf(v);
}

__global__ void w3m_kernel(const float* __restrict__ W3, unsigned short* __restrict__ w3m) {
  int gid = blockIdx.x * 256 + threadIdx.x;
  if (gid >= 10 * 4 * 14 * 64 * 8) return;
  int j = gid & 7;
  int l = (gid >> 3) & 63;
  int rest = gid >> 9;
  int c = rest % 14; rest /= 14;
  int g = rest & 3;  int i = rest >> 2;
  int m = l & 15;
  int kb = l >> 4;
  int klocal = c * 32 + kb * 8 + j;
  int tap = klocal >> 4;
  int cil = klocal & 15;
  int ci = g * 16 + cil;
  float v = 0.f;
  if (m == 0 && tap < 27 && ci < 50)
    v = W3[((size_t)i * 50 + ci) * 27 + tap];
  w3m[gid] = f2bf(v);
}

extern "C" void kernel_launch(void* const* d_in, const int* in_sizes, int n_in,
                              void* d_out, int out_size, void* d_ws, size_t ws_size,
                              hipStream_t stream) {
  const float* src = (const float*)d_in[0];
  const float* tgt = (const float*)d_in[1];
  const float* seg = (const float*)d_in[2];
  const float* z0  = (const float*)d_in[3];
  const float* W1  = (const float*)d_in[4];
  const float* W2  = (const float*)d_in[5];
  const float* W3  = (const float*)d_in[6];
  float* out = (float*)d_out;
  float* ws = (float*)d_ws;

  const size_t N = NV;
  float* residual = ws;                       // 1
  float* image    = ws + N;                   // 1
  float* rdb[2]   = { ws + 2 * N, ws + 3 * N };
  float* phib[2]  = { ws + 4 * N, ws + 7 * N };   // 3 each
  float* vbuf     = ws + 10 * N;                  // 3
  float* t1       = ws + 13 * N;                  // 3
  unsigned short* x1b = (unsigned short*)(ws + 19 * N);   // 32N f32 equivalent
  unsigned short* x2b = (unsigned short*)(ws + 51 * N);
  float* wt1      = ws + 83 * N;                  // 42120 f32
  unsigned short* wt2m = (unsigned short*)(wt1 + 42120);
  unsigned short* w3m  = wt2m + (size_t)10 * 4 * 14 * 4 * 64 * 8;

  size_t needed = (83 * N + 42120) * sizeof(float)
                + ((size_t)10 * 4 * 14 * 4 * 64 * 8 + (size_t)10 * 4 * 14 * 64 * 8) * 2;
  if (ws_size < needed) return;

  float* out_image  = out;
  float* out_fields = out + N;
  float* out_grads  = out + 31 * N;
  float* out_resid  = out + 61 * N;
  float* out_rd     = out + 72 * N;

  dim3 blk(256);
  dim3 grdN((unsigned)(N / 256));
  dim3 sgrd(16, 64);
  dim3 cgrd(8, 8, 16);
  dim3 mgrd(4, 16, 16);

  init_kernel<<<grdN, blk, 0, stream>>>(src, z0, residual, image, rdb[0], phib[0], out_resid);
  wt1_kernel<<<(10 * 50 * 3 * 27 + 255) / 256, blk, 0, stream>>>(W1, wt1);
  wt2m_kernel<<<(10 * 4 * 14 * 4 * 64 * 8 + 255) / 256, blk, 0, stream>>>(W2, wt2m);
  w3m_kernel<<<(10 * 4 * 14 * 64 * 8 + 255) / 256, blk, 0, stream>>>(W3, w3m);

  int rc = 0, pc = 0;
  for (int i = 0; i < 10; ++i) {
    gsd_kernel<<<grdN, blk, 0, stream>>>(image, residual, out_grads + (size_t)i * 3 * N, t1);
    smooth_hw<<<sgrd, blk, 0, stream>>>(t1, vbuf, out_fields + (size_t)i * 3 * N);

    conv1_kernel<<<cgrd, blk, 0, stream>>>(residual, image, tgt,
                                           wt1 + (size_t)i * 3 * 27 * 52, x1b);
    conv2_mfma<<<mgrd, blk, 0, stream>>>(x1b, wt2m + (size_t)i * 4 * 14 * 4 * 64 * 8, x2b);
    conv3_mfma<<<mgrd, blk, 0, stream>>>(x2b, w3m + (size_t)i * 4 * 14 * 64 * 8, residual,
                                         out_resid + (size_t)(i + 1) * N);

    float* rdNew = (i == 9) ? out_rd : rdb[1 - rc];
    float* imgNew = (i == 9) ? out_image : image;
    rp_fused_kernel<<<grdN, blk, 0, stream>>>(rdb[rc], vbuf, residual, phib[pc],
                                              phib[1 - pc], src, seg, rdNew, imgNew,
                                              i > 0 ? 1 : 0);
    rc = 1 - rc;
    pc = 1 - pc;
  }
}